// Round 4
// baseline (2348.412 us; speedup 1.0000x reference)
//
#include <hip/hip_runtime.h>
#include <hip/hip_bf16.h>
#include <math.h>

#define NNODES 100000
#define EDIM 128
#define TSLOTS 750000
#define NB 391  // ceil(NNODES/256)

typedef __bf16 bf16x8 __attribute__((ext_vector_type(8)));
typedef __bf16 bf16x4 __attribute__((ext_vector_type(4)));
typedef float f32x4 __attribute__((ext_vector_type(4)));

#define T_SCALE 17.312340490667562f   // 12*log2(e): msg stores t = y*T_SCALE
#define INV_SCALE 0.05776226504666211f // ln2/12
#define EMPTY_V (-3.0701134f)          // log(1e-16)/12

// mish(x) = x*tanh(softplus(x)) = x*(u^2+2u)/(u^2+2u+2), u=e^x
__device__ __forceinline__ float mishf(float x) {
  float u = __expf(fminf(x, 15.f));
  float num = u * (u + 2.f);
  return x * num * __builtin_amdgcn_rcpf(num + 2.f);
}

// ---- fallback helpers ----
__device__ __forceinline__ double exp12(float y) {
  float t = y * 17.312340490667562f;
  t = fminf(fmaxf(t, -20000.f), 20000.f);
  float ti = floorf(t);
  float m = exp2f(t - ti);
  int ei = (int)ti;
  ei = ei < -1000 ? -1000 : (ei > 1000 ? 1000 : ei);
  double sc = __longlong_as_double(((long long)(1023 + ei)) << 52);
  return (double)m * sc;
}
__device__ __forceinline__ float logS12(double S) {
  if (!(S > 0.0)) return EMPTY_V;
  long long b = __double_as_longlong(S);
  int e2 = (int)((b >> 52) & 0x7FF) - 1023;
  float mf = __uint_as_float(0x3F800000u | (unsigned)((b >> 29) & 0x7FFFFF));
  return ((float)e2 + log2f(mf)) * INV_SCALE;
}

__global__ void k_sentinel(float* out, int n) {
  int i = blockIdx.x * 256 + threadIdx.x;
  if (i < n) out[i] = 1.0e6f;
}

struct TransDesc {
  const float* src[8];
  __bf16* dst[8];
  int R[8];
  int C[8];
  int tstart[9];
};

__global__ void k_transpose_all(TransDesc td) {
  __shared__ float tile[32][33];
  int b = blockIdx.x;
  int m = 0;
  while (m < 7 && b >= td.tstart[m + 1]) m++;
  int t = b - td.tstart[m];
  int R = td.R[m], C = td.C[m];
  int tcols = C >> 5;
  int by = t / tcols, bx = t - by * tcols;
  int tx = threadIdx.x & 31, ty = threadIdx.x >> 5;
  const float* src = td.src[m];
  __bf16* dst = td.dst[m];
  for (int i = 0; i < 32; i += 8)
    tile[ty + i][tx] = src[(size_t)(by * 32 + ty + i) * C + bx * 32 + tx];
  __syncthreads();
  for (int i = 0; i < 32; i += 8)
    dst[(size_t)(bx * 32 + ty + i) * R + by * 32 + tx] = (__bf16)tile[tx][ty + i];
}

// ================= CSR build =================
__device__ __forceinline__ int slot_node(int s, const int* at, const int* cl, const int* on) {
  if (s < 300000) return at[s];
  if (s < 450000) return cl[s - 300000];
  return on[s - 450000];
}

__global__ void k_count(const int* __restrict__ at, const int* __restrict__ cl,
                        const int* __restrict__ on, int* __restrict__ cnt) {
  int s = blockIdx.x * 256 + threadIdx.x;
  if (s >= TSLOTS) return;
  atomicAdd(&cnt[slot_node(s, at, cl, on)], 1);
}

__global__ void k_bsum(const int* __restrict__ cnt, int* __restrict__ bsum) {
  __shared__ int sm[256];
  int n = blockIdx.x * 256 + threadIdx.x;
  sm[threadIdx.x] = (n < NNODES) ? cnt[n] : 0;
  __syncthreads();
  for (int st = 128; st > 0; st >>= 1) {
    if (threadIdx.x < st) sm[threadIdx.x] += sm[threadIdx.x + st];
    __syncthreads();
  }
  if (threadIdx.x == 0) bsum[blockIdx.x] = sm[0];
}

// parallel scan over NB block sums (512 threads, 1 block)
__global__ void k_bscan(const int* __restrict__ bsum, int* __restrict__ bpre,
                        int* __restrict__ off) {
  __shared__ int sm[512];
  int t = threadIdx.x;
  int v = (t < NB) ? bsum[t] : 0;
  sm[t] = v;
  __syncthreads();
  for (int st = 1; st < 512; st <<= 1) {
    int x = (t >= st) ? sm[t - st] : 0;
    __syncthreads();
    sm[t] += x;
    __syncthreads();
  }
  if (t < NB) bpre[t] = sm[t] - v;
  if (t == NB - 1) off[NNODES] = sm[t];
}

__global__ void k_off(const int* __restrict__ cnt, const int* __restrict__ bpre,
                      int* __restrict__ off) {
  __shared__ int sm[256];
  int n = blockIdx.x * 256 + threadIdx.x;
  int v = (n < NNODES) ? cnt[n] : 0;
  sm[threadIdx.x] = v;
  __syncthreads();
  for (int st = 1; st < 256; st <<= 1) {
    int t = (threadIdx.x >= st) ? sm[threadIdx.x - st] : 0;
    __syncthreads();
    sm[threadIdx.x] += t;
    __syncthreads();
  }
  if (n < NNODES) off[n] = bpre[blockIdx.x] + sm[threadIdx.x] - v;
}

// perm[slot] = CSR position for that slot
__global__ void k_fill(const int* __restrict__ at, const int* __restrict__ cl,
                       const int* __restrict__ on, const int* __restrict__ off,
                       int* __restrict__ cnt, int* __restrict__ perm) {
  int s = blockIdx.x * 256 + threadIdx.x;
  if (s >= TSLOTS) return;
  int node = slot_node(s, at, cl, on);
  int pos = atomicAdd(&cnt[node], -1) - 1;  // 0..deg-1
  perm[s] = off[node] + pos;
}

// ================= relation kernels: write t=y*T_SCALE fp16 rows in CSR order =================
__global__ __launch_bounds__(256, 2) void k_rel2(
    const float* __restrict__ h, const int* __restrict__ av,
    const __bf16* __restrict__ wt1, const float* __restrict__ b1,
    const __bf16* __restrict__ wt2, const float* __restrict__ b2,
    _Float16* __restrict__ msg, const int* __restrict__ permrel, int A) {
  __shared__ __align__(16) __bf16 xs[64][264];
  __shared__ int avs[128];
  __shared__ int prm[128];
  const int tid = threadIdx.x;
  const int lane = tid & 63;
  const int w = tid >> 6;
  const int row0 = blockIdx.x * 64;

  if (tid < 128) {
    int i2 = row0 * 2 + tid;
    avs[tid] = (i2 < 2 * A) ? av[i2] : 0;
    prm[tid] = (i2 < 2 * A) ? permrel[i2] : 0;
  }
  for (int i = 0; i < 16; ++i) {
    int s = tid + i * 256;
    int r = s >> 6, o = s & 63;
    int a = row0 + r;
    float4 f = {0.f, 0.f, 0.f, 0.f};
    if (a < A) {
      int node = av[2 * a + (o >> 5)];
      f = *(const float4*)(h + (size_t)node * 128 + (o & 31) * 4);
    }
    bf16x4 p = {(__bf16)f.x, (__bf16)f.y, (__bf16)f.z, (__bf16)f.w};
    *(bf16x4*)&xs[r][o * 4] = p;
  }
  __syncthreads();

  const int lhi = lane >> 4, llo = lane & 15;
  const int cb = w * 64;

  f32x4 acc1[4][4];
#pragma unroll
  for (int rt = 0; rt < 4; rt++)
#pragma unroll
    for (int ct = 0; ct < 4; ct++) acc1[rt][ct] = (f32x4){0.f, 0.f, 0.f, 0.f};

#pragma unroll
  for (int kk = 0; kk < 8; ++kk) {
    int k = kk * 32 + lhi * 8;
    bf16x8 af[4], bfr[4];
#pragma unroll
    for (int rt = 0; rt < 4; rt++) af[rt] = *(const bf16x8*)&xs[rt * 16 + llo][k];
#pragma unroll
    for (int ct = 0; ct < 4; ct++)
      bfr[ct] = *(const bf16x8*)(wt1 + (size_t)(cb + ct * 16 + llo) * 256 + k);
#pragma unroll
    for (int rt = 0; rt < 4; rt++)
#pragma unroll
      for (int ct = 0; ct < 4; ct++)
        acc1[rt][ct] = __builtin_amdgcn_mfma_f32_16x16x32_bf16(af[rt], bfr[ct], acc1[rt][ct], 0, 0, 0);
  }
  __syncthreads();

  float b1v[4];
#pragma unroll
  for (int ct = 0; ct < 4; ct++) b1v[ct] = b1[cb + ct * 16 + llo];
#pragma unroll
  for (int rt = 0; rt < 4; rt++)
#pragma unroll
    for (int ct = 0; ct < 4; ct++)
#pragma unroll
      for (int i = 0; i < 4; i++)
        xs[rt * 16 + lhi * 4 + i][cb + ct * 16 + llo] = (__bf16)mishf(acc1[rt][ct][i] + b1v[ct]);
  __syncthreads();

  f32x4 acc2[4][4];
#pragma unroll
  for (int rt = 0; rt < 4; rt++)
#pragma unroll
    for (int ct = 0; ct < 4; ct++) acc2[rt][ct] = (f32x4){0.f, 0.f, 0.f, 0.f};

#pragma unroll
  for (int kk = 0; kk < 8; ++kk) {
    int k = kk * 32 + lhi * 8;
    bf16x8 af[4], bfr[4];
#pragma unroll
    for (int rt = 0; rt < 4; rt++) af[rt] = *(const bf16x8*)&xs[rt * 16 + llo][k];
#pragma unroll
    for (int ct = 0; ct < 4; ct++)
      bfr[ct] = *(const bf16x8*)(wt2 + (size_t)(cb + ct * 16 + llo) * 256 + k);
#pragma unroll
    for (int rt = 0; rt < 4; rt++)
#pragma unroll
      for (int ct = 0; ct < 4; ct++)
        acc2[rt][ct] = __builtin_amdgcn_mfma_f32_16x16x32_bf16(af[rt], bfr[ct], acc2[rt][ct], 0, 0, 0);
  }
  __syncthreads();

  float b2v[4];
#pragma unroll
  for (int ct = 0; ct < 4; ct++) b2v[ct] = b2[cb + ct * 16 + llo];
  ushort* zs = (ushort*)&xs[0][0];  // row stride 264 ushorts
#pragma unroll
  for (int rt = 0; rt < 4; rt++)
#pragma unroll
    for (int ct = 0; ct < 4; ct++)
#pragma unroll
      for (int i = 0; i < 4; i++) {
        int r = rt * 16 + lhi * 4 + i;
        int col = cb + ct * 16 + llo;
        union { ushort u; _Float16 f; } cv;
        cv.f = (_Float16)(acc2[rt][ct][i] + b2v[ct]);
        zs[r * 264 + col] = cv.u;
      }
  __syncthreads();

  // write-out: 128 slot-rows x 128 fp16 (t-scaled), scattered to CSR position
  for (int i = 0; i < 8; ++i) {
    int s = tid + i * 256;
    int sr = s >> 4;   // slot-row 0..127
    int c = s & 15;    // 8-feat chunk
    int a = row0 + (sr >> 1);
    if (a < A) {
      int node = avs[sr];
      int rr = sr >> 1, c0 = (sr & 1) * 128 + c * 8;
      const float* hp = h + (size_t)node * 128 + c * 8;
      float4 h0 = *(const float4*)hp;
      float4 h1 = *(const float4*)(hp + 4);
      union { uint4 u; _Float16 f[8]; } zu, yu;
      zu.u = *(const uint4*)&zs[rr * 264 + c0];
      yu.f[0] = (_Float16)(((float)zu.f[0] + h0.x) * T_SCALE);
      yu.f[1] = (_Float16)(((float)zu.f[1] + h0.y) * T_SCALE);
      yu.f[2] = (_Float16)(((float)zu.f[2] + h0.z) * T_SCALE);
      yu.f[3] = (_Float16)(((float)zu.f[3] + h0.w) * T_SCALE);
      yu.f[4] = (_Float16)(((float)zu.f[4] + h1.x) * T_SCALE);
      yu.f[5] = (_Float16)(((float)zu.f[5] + h1.y) * T_SCALE);
      yu.f[6] = (_Float16)(((float)zu.f[6] + h1.z) * T_SCALE);
      yu.f[7] = (_Float16)(((float)zu.f[7] + h1.w) * T_SCALE);
      *(uint4*)(msg + (size_t)prm[sr] * 128 + c * 8) = yu.u;
    }
  }
}

__global__ __launch_bounds__(256, 2) void k_rel1(
    const float* __restrict__ h, const int* __restrict__ av,
    const __bf16* __restrict__ wt1, const float* __restrict__ b1,
    const __bf16* __restrict__ wt2, const float* __restrict__ b2,
    _Float16* __restrict__ msg, const int* __restrict__ permrel, int A) {
  __shared__ __align__(16) __bf16 xs[64][136];
  __shared__ int avs[64];
  __shared__ int prm[64];
  const int tid = threadIdx.x;
  const int lane = tid & 63;
  const int w = tid >> 6;
  const int row0 = blockIdx.x * 64;

  if (tid < 64) {
    int a = row0 + tid;
    avs[tid] = (a < A) ? av[a] : 0;
    prm[tid] = (a < A) ? permrel[a] : 0;
  }
  for (int i = 0; i < 8; ++i) {
    int s = tid + i * 256;
    int r = s >> 5, o = s & 31;
    int a = row0 + r;
    float4 f = {0.f, 0.f, 0.f, 0.f};
    if (a < A) {
      int node = av[a];
      f = *(const float4*)(h + (size_t)node * 128 + o * 4);
    }
    bf16x4 p = {(__bf16)f.x, (__bf16)f.y, (__bf16)f.z, (__bf16)f.w};
    *(bf16x4*)&xs[r][o * 4] = p;
  }
  __syncthreads();

  const int lhi = lane >> 4, llo = lane & 15;
  const int cb = w * 32;

  f32x4 acc1[4][2];
#pragma unroll
  for (int rt = 0; rt < 4; rt++)
#pragma unroll
    for (int ct = 0; ct < 2; ct++) acc1[rt][ct] = (f32x4){0.f, 0.f, 0.f, 0.f};

#pragma unroll
  for (int kk = 0; kk < 4; ++kk) {
    int k = kk * 32 + lhi * 8;
    bf16x8 af[4], bfr[2];
#pragma unroll
    for (int rt = 0; rt < 4; rt++) af[rt] = *(const bf16x8*)&xs[rt * 16 + llo][k];
#pragma unroll
    for (int ct = 0; ct < 2; ct++)
      bfr[ct] = *(const bf16x8*)(wt1 + (size_t)(cb + ct * 16 + llo) * 128 + k);
#pragma unroll
    for (int rt = 0; rt < 4; rt++)
#pragma unroll
      for (int ct = 0; ct < 2; ct++)
        acc1[rt][ct] = __builtin_amdgcn_mfma_f32_16x16x32_bf16(af[rt], bfr[ct], acc1[rt][ct], 0, 0, 0);
  }
  __syncthreads();

  float b1v[2];
#pragma unroll
  for (int ct = 0; ct < 2; ct++) b1v[ct] = b1[cb + ct * 16 + llo];
#pragma unroll
  for (int rt = 0; rt < 4; rt++)
#pragma unroll
    for (int ct = 0; ct < 2; ct++)
#pragma unroll
      for (int i = 0; i < 4; i++)
        xs[rt * 16 + lhi * 4 + i][cb + ct * 16 + llo] = (__bf16)mishf(acc1[rt][ct][i] + b1v[ct]);
  __syncthreads();

  f32x4 acc2[4][2];
#pragma unroll
  for (int rt = 0; rt < 4; rt++)
#pragma unroll
    for (int ct = 0; ct < 2; ct++) acc2[rt][ct] = (f32x4){0.f, 0.f, 0.f, 0.f};

#pragma unroll
  for (int kk = 0; kk < 4; ++kk) {
    int k = kk * 32 + lhi * 8;
    bf16x8 af[4], bfr[2];
#pragma unroll
    for (int rt = 0; rt < 4; rt++) af[rt] = *(const bf16x8*)&xs[rt * 16 + llo][k];
#pragma unroll
    for (int ct = 0; ct < 2; ct++)
      bfr[ct] = *(const bf16x8*)(wt2 + (size_t)(cb + ct * 16 + llo) * 128 + k);
#pragma unroll
    for (int rt = 0; rt < 4; rt++)
#pragma unroll
      for (int ct = 0; ct < 2; ct++)
        acc2[rt][ct] = __builtin_amdgcn_mfma_f32_16x16x32_bf16(af[rt], bfr[ct], acc2[rt][ct], 0, 0, 0);
  }
  __syncthreads();

  float b2v[2];
#pragma unroll
  for (int ct = 0; ct < 2; ct++) b2v[ct] = b2[cb + ct * 16 + llo];
  ushort* zs = (ushort*)&xs[0][0];  // row stride 136
#pragma unroll
  for (int rt = 0; rt < 4; rt++)
#pragma unroll
    for (int ct = 0; ct < 2; ct++)
#pragma unroll
      for (int i = 0; i < 4; i++) {
        int r = rt * 16 + lhi * 4 + i;
        int col = cb + ct * 16 + llo;
        union { ushort u; _Float16 f; } cv;
        cv.f = (_Float16)(acc2[rt][ct][i] + b2v[ct]);
        zs[r * 136 + col] = cv.u;
      }
  __syncthreads();

  for (int i = 0; i < 4; ++i) {
    int s = tid + i * 256;
    int sr = s >> 4;  // 0..63
    int c = s & 15;
    int a = row0 + sr;
    if (a < A) {
      int node = avs[sr];
      const float* hp = h + (size_t)node * 128 + c * 8;
      float4 h0 = *(const float4*)hp;
      float4 h1 = *(const float4*)(hp + 4);
      union { uint4 u; _Float16 f[8]; } zu, yu;
      zu.u = *(const uint4*)&zs[sr * 136 + c * 8];
      yu.f[0] = (_Float16)(((float)zu.f[0] + h0.x) * T_SCALE);
      yu.f[1] = (_Float16)(((float)zu.f[1] + h0.y) * T_SCALE);
      yu.f[2] = (_Float16)(((float)zu.f[2] + h0.z) * T_SCALE);
      yu.f[3] = (_Float16)(((float)zu.f[3] + h0.w) * T_SCALE);
      yu.f[4] = (_Float16)(((float)zu.f[4] + h1.x) * T_SCALE);
      yu.f[5] = (_Float16)(((float)zu.f[5] + h1.y) * T_SCALE);
      yu.f[6] = (_Float16)(((float)zu.f[6] + h1.z) * T_SCALE);
      yu.f[7] = (_Float16)(((float)zu.f[7] + h1.w) * T_SCALE);
      *(uint4*)(msg + (size_t)prm[sr] * 128 + c * 8) = yu.u;
    }
  }
}

// update: streaming sequential logsumexp over CSR-ordered msg rows -> MLP
__global__ __launch_bounds__(256, 2) void k_update(
    const float* __restrict__ hin, const _Float16* __restrict__ msg,
    const int* __restrict__ off,
    const __bf16* __restrict__ wt1, const float* __restrict__ b1,
    const __bf16* __restrict__ wt2, const float* __restrict__ b2,
    float* __restrict__ hout) {
  __shared__ __align__(16) __bf16 xs[64][264];
  const int tid = threadIdx.x;
  const int lane = tid & 63;
  const int w = tid >> 6;
  const int node0 = blockIdx.x * 64;

  // h staging (cols 128..255)
  for (int i = 0; i < 8; ++i) {
    int s = tid + i * 256;
    int r = s >> 5, o = s & 31;
    int n = node0 + r;
    float4 f = {0.f, 0.f, 0.f, 0.f};
    if (n < NNODES) f = *(const float4*)(hin + (size_t)n * 128 + o * 4);
    bf16x4 p = {(__bf16)f.x, (__bf16)f.y, (__bf16)f.z, (__bf16)f.w};
    *(bf16x4*)&xs[r][128 + o * 4] = p;
  }

  // aggregation: wave w streams rows [off[n0], off[n0+16]) sequentially
  {
    int n0 = node0 + w * 16;
    int cnt16 = NNODES - n0;
    if (cnt16 > 16) cnt16 = 16;
    if (cnt16 < 0) cnt16 = 0;
    int j = 0;
    float m0 = -1e30f, s0 = 0.f, m1 = -1e30f, s1 = 0.f;
    if (cnt16 > 0) {
      int base = off[n0];
      int endAll = off[n0 + cnt16];
      uint pre[8];
#pragma unroll
      for (int d = 0; d < 8; ++d)
        pre[d] = (base + d < endAll) ? *(const uint*)(msg + (size_t)(base + d) * 128 + lane * 2) : 0u;
      int lp = base + 8;
      int nodeEnd = off[n0 + 1];
      for (int r = base; r < endAll; ++r) {
        while (r >= nodeEnd) {  // finalize node j (handles empty nodes too)
          float v0 = (s0 > 0.f) ? (m0 + log2f(s0)) * INV_SCALE : EMPTY_V;
          float v1 = (s1 > 0.f) ? (m1 + log2f(s1)) * INV_SCALE : EMPTY_V;
          union { uint u; __bf16 b[2]; } pk;
          pk.b[0] = (__bf16)v0;
          pk.b[1] = (__bf16)v1;
          *(uint*)&xs[w * 16 + j][2 * lane] = pk.u;
          m0 = -1e30f; s0 = 0.f; m1 = -1e30f; s1 = 0.f;
          ++j;
          nodeEnd = off[n0 + j + 1];
        }
        uint cur = pre[(r - base) & 7];
        if (lp < endAll)
          pre[(r - base) & 7] = *(const uint*)(msg + (size_t)lp * 128 + lane * 2);
        ++lp;
        union { uint u; _Float16 f[2]; } q;
        q.u = cur;
        float t0 = (float)q.f[0], t1 = (float)q.f[1];
        float nm0 = fmaxf(m0, t0), nm1 = fmaxf(m1, t1);
        s0 = s0 * exp2f(m0 - nm0) + exp2f(t0 - nm0);
        s1 = s1 * exp2f(m1 - nm1) + exp2f(t1 - nm1);
        m0 = nm0; m1 = nm1;
      }
    }
    // finalize remaining nodes (incl. trailing empties), pad to 16 rows
    for (; j < 16; ++j) {
      float v0 = (j < cnt16 && s0 > 0.f) ? (m0 + log2f(s0)) * INV_SCALE : EMPTY_V;
      float v1 = (j < cnt16 && s1 > 0.f) ? (m1 + log2f(s1)) * INV_SCALE : EMPTY_V;
      union { uint u; __bf16 b[2]; } pk;
      pk.b[0] = (__bf16)v0;
      pk.b[1] = (__bf16)v1;
      *(uint*)&xs[w * 16 + j][2 * lane] = pk.u;
      m0 = -1e30f; s0 = 0.f; m1 = -1e30f; s1 = 0.f;
    }
  }
  __syncthreads();

  const int lhi = lane >> 4, llo = lane & 15;
  const int cb = w * 64;

  f32x4 acc1[4][4];
#pragma unroll
  for (int rt = 0; rt < 4; rt++)
#pragma unroll
    for (int ct = 0; ct < 4; ct++) acc1[rt][ct] = (f32x4){0.f, 0.f, 0.f, 0.f};

#pragma unroll
  for (int kk = 0; kk < 8; ++kk) {
    int k = kk * 32 + lhi * 8;
    bf16x8 af[4], bfr[4];
#pragma unroll
    for (int rt = 0; rt < 4; rt++) af[rt] = *(const bf16x8*)&xs[rt * 16 + llo][k];
#pragma unroll
    for (int ct = 0; ct < 4; ct++)
      bfr[ct] = *(const bf16x8*)(wt1 + (size_t)(cb + ct * 16 + llo) * 256 + k);
#pragma unroll
    for (int rt = 0; rt < 4; rt++)
#pragma unroll
      for (int ct = 0; ct < 4; ct++)
        acc1[rt][ct] = __builtin_amdgcn_mfma_f32_16x16x32_bf16(af[rt], bfr[ct], acc1[rt][ct], 0, 0, 0);
  }
  __syncthreads();

  float b1v[4];
#pragma unroll
  for (int ct = 0; ct < 4; ct++) b1v[ct] = b1[cb + ct * 16 + llo];
#pragma unroll
  for (int rt = 0; rt < 4; rt++)
#pragma unroll
    for (int ct = 0; ct < 4; ct++)
#pragma unroll
      for (int i = 0; i < 4; i++)
        xs[rt * 16 + lhi * 4 + i][cb + ct * 16 + llo] = (__bf16)mishf(acc1[rt][ct][i] + b1v[ct]);
  __syncthreads();

  const int cb2 = w * 32;
  f32x4 acc2[4][2];
#pragma unroll
  for (int rt = 0; rt < 4; rt++)
#pragma unroll
    for (int ct = 0; ct < 2; ct++) acc2[rt][ct] = (f32x4){0.f, 0.f, 0.f, 0.f};

#pragma unroll
  for (int kk = 0; kk < 8; ++kk) {
    int k = kk * 32 + lhi * 8;
    bf16x8 af[4], bfr[2];
#pragma unroll
    for (int rt = 0; rt < 4; rt++) af[rt] = *(const bf16x8*)&xs[rt * 16 + llo][k];
#pragma unroll
    for (int ct = 0; ct < 2; ct++)
      bfr[ct] = *(const bf16x8*)(wt2 + (size_t)(cb2 + ct * 16 + llo) * 256 + k);
#pragma unroll
    for (int rt = 0; rt < 4; rt++)
#pragma unroll
      for (int ct = 0; ct < 2; ct++)
        acc2[rt][ct] = __builtin_amdgcn_mfma_f32_16x16x32_bf16(af[rt], bfr[ct], acc2[rt][ct], 0, 0, 0);
  }

  float b2v[2];
#pragma unroll
  for (int ct = 0; ct < 2; ct++) b2v[ct] = b2[cb2 + ct * 16 + llo];
#pragma unroll
  for (int rt = 0; rt < 4; rt++)
#pragma unroll
    for (int i = 0; i < 4; i++) {
      int r = rt * 16 + lhi * 4 + i;
      int n = node0 + r;
      if (n >= NNODES) continue;
#pragma unroll
      for (int ct = 0; ct < 2; ct++) {
        int col = cb2 + ct * 16 + llo;
        size_t idx = (size_t)n * 128 + col;
        hout[idx] = hin[idx] + acc2[rt][ct][i] + b2v[ct];
      }
    }
}

// ================= FALLBACK (atomic path) =================
__global__ __launch_bounds__(256, 2) void k_rel2_a(
    const float* __restrict__ h, const int* __restrict__ av,
    const __bf16* __restrict__ wt1, const float* __restrict__ b1,
    const __bf16* __restrict__ wt2, const float* __restrict__ b2,
    double* __restrict__ seg, int A) {
  __shared__ __align__(16) __bf16 xs[64][264];
  __shared__ int avs[128];
  const int tid = threadIdx.x;
  const int lane = tid & 63;
  const int w = tid >> 6;
  const int row0 = blockIdx.x * 64;

  if (tid < 128) {
    int i2 = row0 * 2 + tid;
    avs[tid] = (i2 < 2 * A) ? av[i2] : 0;
  }
  for (int i = 0; i < 16; ++i) {
    int s = tid + i * 256;
    int r = s >> 6, o = s & 63;
    int a = row0 + r;
    float4 f = {0.f, 0.f, 0.f, 0.f};
    if (a < A) {
      int node = av[2 * a + (o >> 5)];
      f = *(const float4*)(h + (size_t)node * 128 + (o & 31) * 4);
    }
    bf16x4 p = {(__bf16)f.x, (__bf16)f.y, (__bf16)f.z, (__bf16)f.w};
    *(bf16x4*)&xs[r][o * 4] = p;
  }
  __syncthreads();
  const int lhi = lane >> 4, llo = lane & 15;
  const int cb = w * 64;
  f32x4 acc1[4][4];
#pragma unroll
  for (int rt = 0; rt < 4; rt++)
#pragma unroll
    for (int ct = 0; ct < 4; ct++) acc1[rt][ct] = (f32x4){0.f, 0.f, 0.f, 0.f};
#pragma unroll
  for (int kk = 0; kk < 8; ++kk) {
    int k = kk * 32 + lhi * 8;
    bf16x8 af[4], bfr[4];
#pragma unroll
    for (int rt = 0; rt < 4; rt++) af[rt] = *(const bf16x8*)&xs[rt * 16 + llo][k];
#pragma unroll
    for (int ct = 0; ct < 4; ct++)
      bfr[ct] = *(const bf16x8*)(wt1 + (size_t)(cb + ct * 16 + llo) * 256 + k);
#pragma unroll
    for (int rt = 0; rt < 4; rt++)
#pragma unroll
      for (int ct = 0; ct < 4; ct++)
        acc1[rt][ct] = __builtin_amdgcn_mfma_f32_16x16x32_bf16(af[rt], bfr[ct], acc1[rt][ct], 0, 0, 0);
  }
  __syncthreads();
  float b1v[4];
#pragma unroll
  for (int ct = 0; ct < 4; ct++) b1v[ct] = b1[cb + ct * 16 + llo];
#pragma unroll
  for (int rt = 0; rt < 4; rt++)
#pragma unroll
    for (int ct = 0; ct < 4; ct++)
#pragma unroll
      for (int i = 0; i < 4; i++)
        xs[rt * 16 + lhi * 4 + i][cb + ct * 16 + llo] = (__bf16)mishf(acc1[rt][ct][i] + b1v[ct]);
  __syncthreads();
  f32x4 acc2[4][4];
#pragma unroll
  for (int rt = 0; rt < 4; rt++)
#pragma unroll
    for (int ct = 0; ct < 4; ct++) acc2[rt][ct] = (f32x4){0.f, 0.f, 0.f, 0.f};
#pragma unroll
  for (int kk = 0; kk < 8; ++kk) {
    int k = kk * 32 + lhi * 8;
    bf16x8 af[4], bfr[4];
#pragma unroll
    for (int rt = 0; rt < 4; rt++) af[rt] = *(const bf16x8*)&xs[rt * 16 + llo][k];
#pragma unroll
    for (int ct = 0; ct < 4; ct++)
      bfr[ct] = *(const bf16x8*)(wt2 + (size_t)(cb + ct * 16 + llo) * 256 + k);
#pragma unroll
    for (int rt = 0; rt < 4; rt++)
#pragma unroll
      for (int ct = 0; ct < 4; ct++)
        acc2[rt][ct] = __builtin_amdgcn_mfma_f32_16x16x32_bf16(af[rt], bfr[ct], acc2[rt][ct], 0, 0, 0);
  }
  float b2v[4];
#pragma unroll
  for (int ct = 0; ct < 4; ct++) b2v[ct] = b2[cb + ct * 16 + llo];
#pragma unroll
  for (int rt = 0; rt < 4; rt++)
#pragma unroll
    for (int i = 0; i < 4; i++) {
      int r = rt * 16 + lhi * 4 + i;
      if (row0 + r >= A) continue;
#pragma unroll
      for (int ct = 0; ct < 4; ct++) {
        int col = cb + ct * 16 + llo;
        int node = avs[2 * r + (col >> 7)];
        size_t fi = (size_t)node * 128 + (col & 127);
        float y = acc2[rt][ct][i] + b2v[ct] + h[fi];
        atomicAdd(&seg[fi], exp12(y));
      }
    }
}

__global__ __launch_bounds__(256, 2) void k_rel1_a(
    const float* __restrict__ h, const int* __restrict__ av,
    const __bf16* __restrict__ wt1, const float* __restrict__ b1,
    const __bf16* __restrict__ wt2, const float* __restrict__ b2,
    double* __restrict__ seg, int A) {
  __shared__ __align__(16) __bf16 xs[64][136];
  __shared__ int avs[64];
  const int tid = threadIdx.x;
  const int lane = tid & 63;
  const int w = tid >> 6;
  const int row0 = blockIdx.x * 64;

  if (tid < 64) {
    int a = row0 + tid;
    avs[tid] = (a < A) ? av[a] : 0;
  }
  for (int i = 0; i < 8; ++i) {
    int s = tid + i * 256;
    int r = s >> 5, o = s & 31;
    int a = row0 + r;
    float4 f = {0.f, 0.f, 0.f, 0.f};
    if (a < A) {
      int node = av[a];
      f = *(const float4*)(h + (size_t)node * 128 + o * 4);
    }
    bf16x4 p = {(__bf16)f.x, (__bf16)f.y, (__bf16)f.z, (__bf16)f.w};
    *(bf16x4*)&xs[r][o * 4] = p;
  }
  __syncthreads();
  const int lhi = lane >> 4, llo = lane & 15;
  const int cb = w * 32;
  f32x4 acc1[4][2];
#pragma unroll
  for (int rt = 0; rt < 4; rt++)
#pragma unroll
    for (int ct = 0; ct < 2; ct++) acc1[rt][ct] = (f32x4){0.f, 0.f, 0.f, 0.f};
#pragma unroll
  for (int kk = 0; kk < 4; ++kk) {
    int k = kk * 32 + lhi * 8;
    bf16x8 af[4], bfr[2];
#pragma unroll
    for (int rt = 0; rt < 4; rt++) af[rt] = *(const bf16x8*)&xs[rt * 16 + llo][k];
#pragma unroll
    for (int ct = 0; ct < 2; ct++)
      bfr[ct] = *(const bf16x8*)(wt1 + (size_t)(cb + ct * 16 + llo) * 128 + k);
#pragma unroll
    for (int rt = 0; rt < 4; rt++)
#pragma unroll
      for (int ct = 0; ct < 2; ct++)
        acc1[rt][ct] = __builtin_amdgcn_mfma_f32_16x16x32_bf16(af[rt], bfr[ct], acc1[rt][ct], 0, 0, 0);
  }
  __syncthreads();
  float b1v[2];
#pragma unroll
  for (int ct = 0; ct < 2; ct++) b1v[ct] = b1[cb + ct * 16 + llo];
#pragma unroll
  for (int rt = 0; rt < 4; rt++)
#pragma unroll
    for (int ct = 0; ct < 2; ct++)
#pragma unroll
      for (int i = 0; i < 4; i++)
        xs[rt * 16 + lhi * 4 + i][cb + ct * 16 + llo] = (__bf16)mishf(acc1[rt][ct][i] + b1v[ct]);
  __syncthreads();
  f32x4 acc2[4][2];
#pragma unroll
  for (int rt = 0; rt < 4; rt++)
#pragma unroll
    for (int ct = 0; ct < 2; ct++) acc2[rt][ct] = (f32x4){0.f, 0.f, 0.f, 0.f};
#pragma unroll
  for (int kk = 0; kk < 4; ++kk) {
    int k = kk * 32 + lhi * 8;
    bf16x8 af[4], bfr[2];
#pragma unroll
    for (int rt = 0; rt < 4; rt++) af[rt] = *(const bf16x8*)&xs[rt * 16 + llo][k];
#pragma unroll
    for (int ct = 0; ct < 2; ct++)
      bfr[ct] = *(const bf16x8*)(wt2 + (size_t)(cb + ct * 16 + llo) * 128 + k);
#pragma unroll
    for (int rt = 0; rt < 4; rt++)
#pragma unroll
      for (int ct = 0; ct < 2; ct++)
        acc2[rt][ct] = __builtin_amdgcn_mfma_f32_16x16x32_bf16(af[rt], bfr[ct], acc2[rt][ct], 0, 0, 0);
  }
  float b2v[2];
#pragma unroll
  for (int ct = 0; ct < 2; ct++) b2v[ct] = b2[cb + ct * 16 + llo];
#pragma unroll
  for (int rt = 0; rt < 4; rt++)
#pragma unroll
    for (int i = 0; i < 4; i++) {
      int r = rt * 16 + lhi * 4 + i;
      if (row0 + r >= A) continue;
      int node = avs[r];
#pragma unroll
      for (int ct = 0; ct < 2; ct++) {
        int col = cb + ct * 16 + llo;
        size_t fi = (size_t)node * 128 + col;
        float y = acc2[rt][ct][i] + b2v[ct] + h[fi];
        atomicAdd(&seg[fi], exp12(y));
      }
    }
}

__global__ __launch_bounds__(256, 2) void k_update_a(
    const float* __restrict__ hin, const double* __restrict__ seg,
    const __bf16* __restrict__ wt1, const float* __restrict__ b1,
    const __bf16* __restrict__ wt2, const float* __restrict__ b2,
    float* __restrict__ hout) {
  __shared__ __align__(16) __bf16 xs[64][264];
  const int tid = threadIdx.x;
  const int lane = tid & 63;
  const int w = tid >> 6;
  const int node0 = blockIdx.x * 64;

  for (int i = 0; i < 32; ++i) {
    int e = tid + i * 256;
    int r = e >> 7, f = e & 127;
    int n = node0 + r;
    float v = 0.f;
    if (n < NNODES) v = logS12(seg[(size_t)n * 128 + f]);
    xs[r][f] = (__bf16)v;
  }
  for (int i = 0; i < 8; ++i) {
    int s = tid + i * 256;
    int r = s >> 5, o = s & 31;
    int n = node0 + r;
    float4 f = {0.f, 0.f, 0.f, 0.f};
    if (n < NNODES) f = *(const float4*)(hin + (size_t)n * 128 + o * 4);
    bf16x4 p = {(__bf16)f.x, (__bf16)f.y, (__bf16)f.z, (__bf16)f.w};
    *(bf16x4*)&xs[r][128 + o * 4] = p;
  }
  __syncthreads();
  const int lhi = lane >> 4, llo = lane & 15;
  const int cb = w * 64;
  f32x4 acc1[4][4];
#pragma unroll
  for (int rt = 0; rt < 4; rt++)
#pragma unroll
    for (int ct = 0; ct < 4; ct++) acc1[rt][ct] = (f32x4){0.f, 0.f, 0.f, 0.f};
#pragma unroll
  for (int kk = 0; kk < 8; ++kk) {
    int k = kk * 32 + lhi * 8;
    bf16x8 af[4], bfr[4];
#pragma unroll
    for (int rt = 0; rt < 4; rt++) af[rt] = *(const bf16x8*)&xs[rt * 16 + llo][k];
#pragma unroll
    for (int ct = 0; ct < 4; ct++)
      bfr[ct] = *(const bf16x8*)(wt1 + (size_t)(cb + ct * 16 + llo) * 256 + k);
#pragma unroll
    for (int rt = 0; rt < 4; rt++)
#pragma unroll
      for (int ct = 0; ct < 4; ct++)
        acc1[rt][ct] = __builtin_amdgcn_mfma_f32_16x16x32_bf16(af[rt], bfr[ct], acc1[rt][ct], 0, 0, 0);
  }
  __syncthreads();
  float b1v[4];
#pragma unroll
  for (int ct = 0; ct < 4; ct++) b1v[ct] = b1[cb + ct * 16 + llo];
#pragma unroll
  for (int rt = 0; rt < 4; rt++)
#pragma unroll
    for (int ct = 0; ct < 4; ct++)
#pragma unroll
      for (int i = 0; i < 4; i++)
        xs[rt * 16 + lhi * 4 + i][cb + ct * 16 + llo] = (__bf16)mishf(acc1[rt][ct][i] + b1v[ct]);
  __syncthreads();
  const int cb2 = w * 32;
  f32x4 acc2[4][2];
#pragma unroll
  for (int rt = 0; rt < 4; rt++)
#pragma unroll
    for (int ct = 0; ct < 2; ct++) acc2[rt][ct] = (f32x4){0.f, 0.f, 0.f, 0.f};
#pragma unroll
  for (int kk = 0; kk < 8; ++kk) {
    int k = kk * 32 + lhi * 8;
    bf16x8 af[4], bfr[2];
#pragma unroll
    for (int rt = 0; rt < 4; rt++) af[rt] = *(const bf16x8*)&xs[rt * 16 + llo][k];
#pragma unroll
    for (int ct = 0; ct < 2; ct++)
      bfr[ct] = *(const bf16x8*)(wt2 + (size_t)(cb2 + ct * 16 + llo) * 256 + k);
#pragma unroll
    for (int rt = 0; rt < 4; rt++)
#pragma unroll
      for (int ct = 0; ct < 2; ct++)
        acc2[rt][ct] = __builtin_amdgcn_mfma_f32_16x16x32_bf16(af[rt], bfr[ct], acc2[rt][ct], 0, 0, 0);
  }
  float b2v[2];
#pragma unroll
  for (int ct = 0; ct < 2; ct++) b2v[ct] = b2[cb2 + ct * 16 + llo];
#pragma unroll
  for (int rt = 0; rt < 4; rt++)
#pragma unroll
    for (int i = 0; i < 4; i++) {
      int r = rt * 16 + lhi * 4 + i;
      int n = node0 + r;
      if (n >= NNODES) continue;
#pragma unroll
      for (int ct = 0; ct < 2; ct++) {
        int col = cb2 + ct * 16 + llo;
        size_t idx = (size_t)n * 128 + col;
        hout[idx] = hin[idx] + acc2[rt][ct][i] + b2v[ct];
      }
    }
}

extern "C" void kernel_launch(void* const* d_in, const int* in_sizes, int n_in,
                              void* d_out, int out_size, void* d_ws, size_t ws_size,
                              hipStream_t stream) {
  const float* h0 = (const float*)d_in[0];
  const int* at = (const int*)d_in[1];
  const float* w_in_at = (const float*)d_in[2];
  const float* b_in_at = (const float*)d_in[3];
  const float* w_out_at = (const float*)d_in[4];
  const float* b_out_at = (const float*)d_in[5];
  const int* cl = (const int*)d_in[6];
  const float* w_in_cl = (const float*)d_in[7];
  const float* b_in_cl = (const float*)d_in[8];
  const float* w_out_cl = (const float*)d_in[9];
  const float* b_out_cl = (const float*)d_in[10];
  const int* on = (const int*)d_in[11];
  const float* w_in_on = (const float*)d_in[12];
  const float* b_in_on = (const float*)d_in[13];
  const float* w_out_on = (const float*)d_in[14];
  const float* b_out_on = (const float*)d_in[15];
  const float* w_u_in = (const float*)d_in[16];
  const float* b_u_in = (const float*)d_in[17];
  const float* w_u_out = (const float*)d_in[18];
  const float* b_u_out = (const float*)d_in[19];

  float* hout = (float*)d_out;
  char* ws = (char*)d_ws;

  const size_t MSG_B = (size_t)TSLOTS * 128 * 2;  // 192,000,000
  const size_t OFF_B = 400016;
  const size_t CNT_B = 400000;
  const size_t BS_B = 1568;
  const size_t REQ2 = MSG_B + OFF_B + CNT_B + BS_B * 2 + 3000000 + 786432;
  const size_t SEG_B = (size_t)NNODES * 128 * 8;
  const size_t REQ1 = SEG_B + 786432;

  const int grid_rel = (150000 + 63) / 64;
  const int grid_upd = (NNODES + 63) / 64;
  const int grid_slots = (TSLOTS + 255) / 256;

  TransDesc td;
  const float* srcs[8] = {w_in_at, w_out_at, w_in_on, w_out_on, w_u_in, w_u_out, w_in_cl, w_out_cl};
  int Rs[8] = {256, 256, 256, 256, 256, 256, 128, 128};
  int Cs[8] = {256, 256, 256, 256, 256, 128, 128, 128};

  if (ws_size >= REQ2) {
    _Float16* msg = (_Float16*)ws;
    int* off = (int*)(ws + MSG_B);
    int* cnt = (int*)(ws + MSG_B + OFF_B);
    int* bsum = (int*)(ws + MSG_B + OFF_B + CNT_B);
    int* bpre = (int*)(ws + MSG_B + OFF_B + CNT_B + BS_B);
    int* perm = (int*)(ws + MSG_B + OFF_B + CNT_B + 2 * BS_B);
    __bf16* wt = (__bf16*)(ws + MSG_B + OFF_B + CNT_B + 2 * BS_B + 3000000);

    __bf16* wt_in_at = wt;
    __bf16* wt_out_at = wt + 65536;
    __bf16* wt_in_on = wt + 131072;
    __bf16* wt_out_on = wt + 196608;
    __bf16* wt_u_in = wt + 262144;
    __bf16* wt_u_out = wt + 327680;
    __bf16* wt_in_cl = wt + 360448;
    __bf16* wt_out_cl = wt + 376832;
    __bf16* dsts[8] = {wt_in_at, wt_out_at, wt_in_on, wt_out_on, wt_u_in, wt_u_out, wt_in_cl, wt_out_cl};
    int ts = 0;
    for (int m = 0; m < 8; ++m) {
      td.src[m] = srcs[m]; td.dst[m] = dsts[m]; td.R[m] = Rs[m]; td.C[m] = Cs[m];
      td.tstart[m] = ts; ts += (Rs[m] / 32) * (Cs[m] / 32);
    }
    td.tstart[8] = ts;
    k_transpose_all<<<384, 256, 0, stream>>>(td);

    hipMemsetAsync(cnt, 0, CNT_B, stream);
    k_count<<<grid_slots, 256, 0, stream>>>(at, cl, on, cnt);
    k_bsum<<<NB, 256, 0, stream>>>(cnt, bsum);
    k_bscan<<<1, 512, 0, stream>>>(bsum, bpre, off);
    k_off<<<NB, 256, 0, stream>>>(cnt, bpre, off);
    k_fill<<<grid_slots, 256, 0, stream>>>(at, cl, on, off, cnt, perm);

    const int* perm_at = perm;
    const int* perm_cl = perm + 300000;
    const int* perm_on = perm + 450000;

    for (int l = 0; l < 4; ++l) {
      const float* hs = (l == 0) ? h0 : hout;
      k_rel2<<<grid_rel, 256, 0, stream>>>(hs, at, wt_in_at, b_in_at, wt_out_at, b_out_at, msg, perm_at, 150000);
      k_rel1<<<grid_rel, 256, 0, stream>>>(hs, cl, wt_in_cl, b_in_cl, wt_out_cl, b_out_cl, msg, perm_cl, 150000);
      k_rel2<<<grid_rel, 256, 0, stream>>>(hs, on, wt_in_on, b_in_on, wt_out_on, b_out_on, msg, perm_on, 150000);
      k_update<<<grid_upd, 256, 0, stream>>>(hs, msg, off, wt_u_in, b_u_in, wt_u_out, b_u_out, hout);
    }
  } else if (ws_size >= REQ1) {
    double* seg = (double*)ws;
    __bf16* wt = (__bf16*)(ws + SEG_B);
    __bf16* wt_in_at = wt;
    __bf16* wt_out_at = wt + 65536;
    __bf16* wt_in_on = wt + 131072;
    __bf16* wt_out_on = wt + 196608;
    __bf16* wt_u_in = wt + 262144;
    __bf16* wt_u_out = wt + 327680;
    __bf16* wt_in_cl = wt + 360448;
    __bf16* wt_out_cl = wt + 376832;
    __bf16* dsts[8] = {wt_in_at, wt_out_at, wt_in_on, wt_out_on, wt_u_in, wt_u_out, wt_in_cl, wt_out_cl};
    int ts = 0;
    for (int m = 0; m < 8; ++m) {
      td.src[m] = srcs[m]; td.dst[m] = dsts[m]; td.R[m] = Rs[m]; td.C[m] = Cs[m];
      td.tstart[m] = ts; ts += (Rs[m] / 32) * (Cs[m] / 32);
    }
    td.tstart[8] = ts;
    k_transpose_all<<<384, 256, 0, stream>>>(td);

    for (int l = 0; l < 4; ++l) {
      const float* hs = (l == 0) ? h0 : hout;
      hipMemsetAsync(seg, 0, SEG_B, stream);
      k_rel2_a<<<grid_rel, 256, 0, stream>>>(hs, at, wt_in_at, b_in_at, wt_out_at, b_out_at, seg, 150000);
      k_rel1_a<<<grid_rel, 256, 0, stream>>>(hs, cl, wt_in_cl, b_in_cl, wt_out_cl, b_out_cl, seg, 150000);
      k_rel2_a<<<grid_rel, 256, 0, stream>>>(hs, on, wt_in_on, b_in_on, wt_out_on, b_out_on, seg, 150000);
      k_update_a<<<grid_upd, 256, 0, stream>>>(hs, seg, wt_u_in, b_u_in, wt_u_out, b_u_out, hout);
    }
  } else {
    k_sentinel<<<(out_size + 255) / 256, 256, 0, stream>>>((float*)d_out, out_size);
  }
}

// Round 5
// 1904.931 us; speedup vs baseline: 1.2328x; 1.2328x over previous
//
#include <hip/hip_runtime.h>
#include <hip/hip_bf16.h>
#include <math.h>

#define NNODES 100000
#define EDIM 128
#define TSLOTS 750000
#define NB 391  // ceil(NNODES/256)

typedef __bf16 bf16x8 __attribute__((ext_vector_type(8)));
typedef __bf16 bf16x4 __attribute__((ext_vector_type(4)));
typedef float f32x4 __attribute__((ext_vector_type(4)));

#define T_SCALE 17.312340490667562f    // 12*log2(e): msg stores t = y*T_SCALE
#define INV_SCALE 0.05776226504666211f // ln2/12
#define EMPTY_V (-3.0701134f)          // log(1e-16)/12

// mish(x) = x*tanh(softplus(x)) = x*(u^2+2u)/(u^2+2u+2), u=e^x
__device__ __forceinline__ float mishf(float x) {
  float u = __expf(fminf(x, 15.f));
  float num = u * (u + 2.f);
  return x * num * __builtin_amdgcn_rcpf(num + 2.f);
}

// 2^t as double (t pre-scaled by 12*log2e), fp32 exp2 + exponent bit-pack
__device__ __forceinline__ double exp12t(float t) {
  t = fmaxf(t, -20000.f);
  float ti = floorf(t);
  float m = exp2f(t - ti);
  int ei = (int)ti;
  ei = ei < -1000 ? -1000 : (ei > 1000 ? 1000 : ei);
  return (double)m * __longlong_as_double(((long long)(1023 + ei)) << 52);
}

// log(S)*ln2/12 via fp64 bit extraction; S<=0 (empty) -> log(1e-16)/12
__device__ __forceinline__ float logS12(double S) {
  if (!(S > 0.0)) return EMPTY_V;
  long long b = __double_as_longlong(S);
  int e2 = (int)((b >> 52) & 0x7FF) - 1023;
  float mf = __uint_as_float(0x3F800000u | (unsigned)((b >> 29) & 0x7FFFFF));
  return ((float)e2 + log2f(mf)) * INV_SCALE;
}

__global__ void k_sentinel(float* out, int n) {
  int i = blockIdx.x * 256 + threadIdx.x;
  if (i < n) out[i] = 1.0e6f;
}

// h0 (fp32) -> hb (bf16)
__global__ void k_init(const float* __restrict__ h0, __bf16* __restrict__ hb, int n8) {
  int i = blockIdx.x * 256 + threadIdx.x;
  if (i >= n8) return;
  float4 f0 = ((const float4*)h0)[i * 2];
  float4 f1 = ((const float4*)h0)[i * 2 + 1];
  bf16x8 p = {(__bf16)f0.x, (__bf16)f0.y, (__bf16)f0.z, (__bf16)f0.w,
              (__bf16)f1.x, (__bf16)f1.y, (__bf16)f1.z, (__bf16)f1.w};
  *(bf16x8*)(hb + (size_t)i * 8) = p;
}

struct TransDesc {
  const float* src[8];
  __bf16* dst[8];
  int R[8];
  int C[8];
  int tstart[9];
};

__global__ void k_transpose_all(TransDesc td) {
  __shared__ float tile[32][33];
  int b = blockIdx.x;
  int m = 0;
  while (m < 7 && b >= td.tstart[m + 1]) m++;
  int t = b - td.tstart[m];
  int R = td.R[m], C = td.C[m];
  int tcols = C >> 5;
  int by = t / tcols, bx = t - by * tcols;
  int tx = threadIdx.x & 31, ty = threadIdx.x >> 5;
  const float* src = td.src[m];
  __bf16* dst = td.dst[m];
  for (int i = 0; i < 32; i += 8)
    tile[ty + i][tx] = src[(size_t)(by * 32 + ty + i) * C + bx * 32 + tx];
  __syncthreads();
  for (int i = 0; i < 32; i += 8)
    dst[(size_t)(bx * 32 + ty + i) * R + by * 32 + tx] = (__bf16)tile[tx][ty + i];
}

// ================= CSR build =================
__device__ __forceinline__ int slot_node(int s, const int* at, const int* cl, const int* on) {
  if (s < 300000) return at[s];
  if (s < 450000) return cl[s - 300000];
  return on[s - 450000];
}

__global__ void k_count(const int* __restrict__ at, const int* __restrict__ cl,
                        const int* __restrict__ on, int* __restrict__ cnt) {
  int s = blockIdx.x * 256 + threadIdx.x;
  if (s >= TSLOTS) return;
  atomicAdd(&cnt[slot_node(s, at, cl, on)], 1);
}

__global__ void k_bsum(const int* __restrict__ cnt, int* __restrict__ bsum) {
  __shared__ int sm[256];
  int n = blockIdx.x * 256 + threadIdx.x;
  sm[threadIdx.x] = (n < NNODES) ? cnt[n] : 0;
  __syncthreads();
  for (int st = 128; st > 0; st >>= 1) {
    if (threadIdx.x < st) sm[threadIdx.x] += sm[threadIdx.x + st];
    __syncthreads();
  }
  if (threadIdx.x == 0) bsum[blockIdx.x] = sm[0];
}

__global__ void k_bscan(const int* __restrict__ bsum, int* __restrict__ bpre,
                        int* __restrict__ off) {
  __shared__ int sm[512];
  int t = threadIdx.x;
  int v = (t < NB) ? bsum[t] : 0;
  sm[t] = v;
  __syncthreads();
  for (int st = 1; st < 512; st <<= 1) {
    int x = (t >= st) ? sm[t - st] : 0;
    __syncthreads();
    sm[t] += x;
    __syncthreads();
  }
  if (t < NB) bpre[t] = sm[t] - v;
  if (t == NB - 1) off[NNODES] = sm[t];
}

__global__ void k_off(const int* __restrict__ cnt, const int* __restrict__ bpre,
                      int* __restrict__ off) {
  __shared__ int sm[256];
  int n = blockIdx.x * 256 + threadIdx.x;
  int v = (n < NNODES) ? cnt[n] : 0;
  sm[threadIdx.x] = v;
  __syncthreads();
  for (int st = 1; st < 256; st <<= 1) {
    int t = (threadIdx.x >= st) ? sm[threadIdx.x - st] : 0;
    __syncthreads();
    sm[threadIdx.x] += t;
    __syncthreads();
  }
  if (n < NNODES) off[n] = bpre[blockIdx.x] + sm[threadIdx.x] - v;
}

__global__ void k_fill(const int* __restrict__ at, const int* __restrict__ cl,
                       const int* __restrict__ on, const int* __restrict__ off,
                       int* __restrict__ cnt, int* __restrict__ perm) {
  int s = blockIdx.x * 256 + threadIdx.x;
  if (s >= TSLOTS) return;
  int node = slot_node(s, at, cl, on);
  int pos = atomicAdd(&cnt[node], -1) - 1;
  perm[s] = off[node] + pos;
}

// ================= relation kernels =================
__global__ __launch_bounds__(256, 2) void k_rel2(
    const float* __restrict__ hf, const __bf16* __restrict__ hb,
    const int* __restrict__ av,
    const __bf16* __restrict__ wt1, const float* __restrict__ b1,
    const __bf16* __restrict__ wt2, const float* __restrict__ b2,
    _Float16* __restrict__ msg, const int* __restrict__ permrel, int A) {
  __shared__ __align__(16) __bf16 xs[64][264];
  __shared__ int avs[128];
  __shared__ int prm[128];
  const int tid = threadIdx.x;
  const int lane = tid & 63;
  const int w = tid >> 6;
  const int row0 = blockIdx.x * 64;

  if (tid < 128) {
    int i2 = row0 * 2 + tid;
    avs[tid] = (i2 < 2 * A) ? av[i2] : 0;
    prm[tid] = (i2 < 2 * A) ? permrel[i2] : 0;
  }
  if (hb != nullptr) {
    // gather bf16: 64 rows x 256 bf16 = 2048 x 16B chunks
    for (int i = 0; i < 8; ++i) {
      int s = tid + i * 256;
      int r = s >> 5, o = s & 31;
      int a = row0 + r;
      uint4 v = {0, 0, 0, 0};
      if (a < A) {
        int node = av[2 * a + (o >> 4)];
        v = *(const uint4*)(hb + (size_t)node * 128 + (o & 15) * 8);
      }
      *(uint4*)&xs[r][o * 8] = v;
    }
  } else {
    for (int i = 0; i < 16; ++i) {
      int s = tid + i * 256;
      int r = s >> 6, o = s & 63;
      int a = row0 + r;
      float4 f = {0.f, 0.f, 0.f, 0.f};
      if (a < A) {
        int node = av[2 * a + (o >> 5)];
        f = *(const float4*)(hf + (size_t)node * 128 + (o & 31) * 4);
      }
      bf16x4 p = {(__bf16)f.x, (__bf16)f.y, (__bf16)f.z, (__bf16)f.w};
      *(bf16x4*)&xs[r][o * 4] = p;
    }
  }
  __syncthreads();

  const int lhi = lane >> 4, llo = lane & 15;
  const int cb = w * 64;

  f32x4 acc1[4][4];
#pragma unroll
  for (int rt = 0; rt < 4; rt++)
#pragma unroll
    for (int ct = 0; ct < 4; ct++) acc1[rt][ct] = (f32x4){0.f, 0.f, 0.f, 0.f};

#pragma unroll
  for (int kk = 0; kk < 8; ++kk) {
    int k = kk * 32 + lhi * 8;
    bf16x8 af[4], bfr[4];
#pragma unroll
    for (int rt = 0; rt < 4; rt++) af[rt] = *(const bf16x8*)&xs[rt * 16 + llo][k];
#pragma unroll
    for (int ct = 0; ct < 4; ct++)
      bfr[ct] = *(const bf16x8*)(wt1 + (size_t)(cb + ct * 16 + llo) * 256 + k);
#pragma unroll
    for (int rt = 0; rt < 4; rt++)
#pragma unroll
      for (int ct = 0; ct < 4; ct++)
        acc1[rt][ct] = __builtin_amdgcn_mfma_f32_16x16x32_bf16(af[rt], bfr[ct], acc1[rt][ct], 0, 0, 0);
  }
  __syncthreads();

  float b1v[4];
#pragma unroll
  for (int ct = 0; ct < 4; ct++) b1v[ct] = b1[cb + ct * 16 + llo];
#pragma unroll
  for (int rt = 0; rt < 4; rt++)
#pragma unroll
    for (int ct = 0; ct < 4; ct++)
#pragma unroll
      for (int i = 0; i < 4; i++)
        xs[rt * 16 + lhi * 4 + i][cb + ct * 16 + llo] = (__bf16)mishf(acc1[rt][ct][i] + b1v[ct]);
  __syncthreads();

  f32x4 acc2[4][4];
#pragma unroll
  for (int rt = 0; rt < 4; rt++)
#pragma unroll
    for (int ct = 0; ct < 4; ct++) acc2[rt][ct] = (f32x4){0.f, 0.f, 0.f, 0.f};

#pragma unroll
  for (int kk = 0; kk < 8; ++kk) {
    int k = kk * 32 + lhi * 8;
    bf16x8 af[4], bfr[4];
#pragma unroll
    for (int rt = 0; rt < 4; rt++) af[rt] = *(const bf16x8*)&xs[rt * 16 + llo][k];
#pragma unroll
    for (int ct = 0; ct < 4; ct++)
      bfr[ct] = *(const bf16x8*)(wt2 + (size_t)(cb + ct * 16 + llo) * 256 + k);
#pragma unroll
    for (int rt = 0; rt < 4; rt++)
#pragma unroll
      for (int ct = 0; ct < 4; ct++)
        acc2[rt][ct] = __builtin_amdgcn_mfma_f32_16x16x32_bf16(af[rt], bfr[ct], acc2[rt][ct], 0, 0, 0);
  }
  __syncthreads();

  float b2v[4];
#pragma unroll
  for (int ct = 0; ct < 4; ct++) b2v[ct] = b2[cb + ct * 16 + llo];
  ushort* zs = (ushort*)&xs[0][0];  // row stride 264
#pragma unroll
  for (int rt = 0; rt < 4; rt++)
#pragma unroll
    for (int ct = 0; ct < 4; ct++)
#pragma unroll
      for (int i = 0; i < 4; i++) {
        int r = rt * 16 + lhi * 4 + i;
        int col = cb + ct * 16 + llo;
        union { ushort u; _Float16 f; } cv;
        cv.f = (_Float16)(acc2[rt][ct][i] + b2v[ct]);
        zs[r * 264 + col] = cv.u;
      }
  __syncthreads();

  // write-out: 128 slot-rows x 128 fp16 (t-scaled), scattered to CSR position
  for (int i = 0; i < 8; ++i) {
    int s = tid + i * 256;
    int sr = s >> 4;   // slot-row 0..127
    int c = s & 15;    // 8-feat chunk
    int a = row0 + (sr >> 1);
    if (a < A) {
      int node = avs[sr];
      int rr = sr >> 1, c0 = (sr & 1) * 128 + c * 8;
      float hv[8];
      if (hb != nullptr) {
        union { uint4 u; __bf16 b[8]; } hu;
        hu.u = *(const uint4*)(hb + (size_t)node * 128 + c * 8);
#pragma unroll
        for (int k = 0; k < 8; ++k) hv[k] = (float)hu.b[k];
      } else {
        const float* hp = hf + (size_t)node * 128 + c * 8;
        float4 h0 = *(const float4*)hp;
        float4 h1 = *(const float4*)(hp + 4);
        hv[0] = h0.x; hv[1] = h0.y; hv[2] = h0.z; hv[3] = h0.w;
        hv[4] = h1.x; hv[5] = h1.y; hv[6] = h1.z; hv[7] = h1.w;
      }
      union { uint4 u; _Float16 f[8]; } zu, yu;
      zu.u = *(const uint4*)&zs[rr * 264 + c0];
#pragma unroll
      for (int k = 0; k < 8; ++k)
        yu.f[k] = (_Float16)(((float)zu.f[k] + hv[k]) * T_SCALE);
      *(uint4*)(msg + (size_t)prm[sr] * 128 + c * 8) = yu.u;
    }
  }
}

__global__ __launch_bounds__(256, 2) void k_rel1(
    const float* __restrict__ hf, const __bf16* __restrict__ hb,
    const int* __restrict__ av,
    const __bf16* __restrict__ wt1, const float* __restrict__ b1,
    const __bf16* __restrict__ wt2, const float* __restrict__ b2,
    _Float16* __restrict__ msg, const int* __restrict__ permrel, int A) {
  __shared__ __align__(16) __bf16 xs[64][136];
  __shared__ int avs[64];
  __shared__ int prm[64];
  const int tid = threadIdx.x;
  const int lane = tid & 63;
  const int w = tid >> 6;
  const int row0 = blockIdx.x * 64;

  if (tid < 64) {
    int a = row0 + tid;
    avs[tid] = (a < A) ? av[a] : 0;
    prm[tid] = (a < A) ? permrel[a] : 0;
  }
  if (hb != nullptr) {
    // 64 rows x 128 bf16 = 1024 x 16B chunks
    for (int i = 0; i < 4; ++i) {
      int s = tid + i * 256;
      int r = s >> 4, o = s & 15;
      int a = row0 + r;
      uint4 v = {0, 0, 0, 0};
      if (a < A) {
        int node = av[a];
        v = *(const uint4*)(hb + (size_t)node * 128 + o * 8);
      }
      *(uint4*)&xs[r][o * 8] = v;
    }
  } else {
    for (int i = 0; i < 8; ++i) {
      int s = tid + i * 256;
      int r = s >> 5, o = s & 31;
      int a = row0 + r;
      float4 f = {0.f, 0.f, 0.f, 0.f};
      if (a < A) {
        int node = av[a];
        f = *(const float4*)(hf + (size_t)node * 128 + o * 4);
      }
      bf16x4 p = {(__bf16)f.x, (__bf16)f.y, (__bf16)f.z, (__bf16)f.w};
      *(bf16x4*)&xs[r][o * 4] = p;
    }
  }
  __syncthreads();

  const int lhi = lane >> 4, llo = lane & 15;
  const int cb = w * 32;

  f32x4 acc1[4][2];
#pragma unroll
  for (int rt = 0; rt < 4; rt++)
#pragma unroll
    for (int ct = 0; ct < 2; ct++) acc1[rt][ct] = (f32x4){0.f, 0.f, 0.f, 0.f};

#pragma unroll
  for (int kk = 0; kk < 4; ++kk) {
    int k = kk * 32 + lhi * 8;
    bf16x8 af[4], bfr[2];
#pragma unroll
    for (int rt = 0; rt < 4; rt++) af[rt] = *(const bf16x8*)&xs[rt * 16 + llo][k];
#pragma unroll
    for (int ct = 0; ct < 2; ct++)
      bfr[ct] = *(const bf16x8*)(wt1 + (size_t)(cb + ct * 16 + llo) * 128 + k);
#pragma unroll
    for (int rt = 0; rt < 4; rt++)
#pragma unroll
      for (int ct = 0; ct < 2; ct++)
        acc1[rt][ct] = __builtin_amdgcn_mfma_f32_16x16x32_bf16(af[rt], bfr[ct], acc1[rt][ct], 0, 0, 0);
  }
  __syncthreads();

  float b1v[2];
#pragma unroll
  for (int ct = 0; ct < 2; ct++) b1v[ct] = b1[cb + ct * 16 + llo];
#pragma unroll
  for (int rt = 0; rt < 4; rt++)
#pragma unroll
    for (int ct = 0; ct < 2; ct++)
#pragma unroll
      for (int i = 0; i < 4; i++)
        xs[rt * 16 + lhi * 4 + i][cb + ct * 16 + llo] = (__bf16)mishf(acc1[rt][ct][i] + b1v[ct]);
  __syncthreads();

  f32x4 acc2[4][2];
#pragma unroll
  for (int rt = 0; rt < 4; rt++)
#pragma unroll
    for (int ct = 0; ct < 2; ct++) acc2[rt][ct] = (f32x4){0.f, 0.f, 0.f, 0.f};

#pragma unroll
  for (int kk = 0; kk < 4; ++kk) {
    int k = kk * 32 + lhi * 8;
    bf16x8 af[4], bfr[2];
#pragma unroll
    for (int rt = 0; rt < 4; rt++) af[rt] = *(const bf16x8*)&xs[rt * 16 + llo][k];
#pragma unroll
    for (int ct = 0; ct < 2; ct++)
      bfr[ct] = *(const bf16x8*)(wt2 + (size_t)(cb + ct * 16 + llo) * 128 + k);
#pragma unroll
    for (int rt = 0; rt < 4; rt++)
#pragma unroll
      for (int ct = 0; ct < 2; ct++)
        acc2[rt][ct] = __builtin_amdgcn_mfma_f32_16x16x32_bf16(af[rt], bfr[ct], acc2[rt][ct], 0, 0, 0);
  }
  __syncthreads();

  float b2v[2];
#pragma unroll
  for (int ct = 0; ct < 2; ct++) b2v[ct] = b2[cb + ct * 16 + llo];
  ushort* zs = (ushort*)&xs[0][0];  // row stride 136
#pragma unroll
  for (int rt = 0; rt < 4; rt++)
#pragma unroll
    for (int ct = 0; ct < 2; ct++)
#pragma unroll
      for (int i = 0; i < 4; i++) {
        int r = rt * 16 + lhi * 4 + i;
        int col = cb + ct * 16 + llo;
        union { ushort u; _Float16 f; } cv;
        cv.f = (_Float16)(acc2[rt][ct][i] + b2v[ct]);
        zs[r * 136 + col] = cv.u;
      }
  __syncthreads();

  for (int i = 0; i < 4; ++i) {
    int s = tid + i * 256;
    int sr = s >> 4;  // 0..63
    int c = s & 15;
    int a = row0 + sr;
    if (a < A) {
      int node = avs[sr];
      float hv[8];
      if (hb != nullptr) {
        union { uint4 u; __bf16 b[8]; } hu;
        hu.u = *(const uint4*)(hb + (size_t)node * 128 + c * 8);
#pragma unroll
        for (int k = 0; k < 8; ++k) hv[k] = (float)hu.b[k];
      } else {
        const float* hp = hf + (size_t)node * 128 + c * 8;
        float4 h0 = *(const float4*)hp;
        float4 h1 = *(const float4*)(hp + 4);
        hv[0] = h0.x; hv[1] = h0.y; hv[2] = h0.z; hv[3] = h0.w;
        hv[4] = h1.x; hv[5] = h1.y; hv[6] = h1.z; hv[7] = h1.w;
      }
      union { uint4 u; _Float16 f[8]; } zu, yu;
      zu.u = *(const uint4*)&zs[sr * 136 + c * 8];
#pragma unroll
      for (int k = 0; k < 8; ++k)
        yu.f[k] = (_Float16)(((float)zu.f[k] + hv[k]) * T_SCALE);
      *(uint4*)(msg + (size_t)prm[sr] * 128 + c * 8) = yu.u;
    }
  }
}

// update: per-node fp64 sum of 2^t over CSR-contiguous msg rows (batch-4, static regs),
// then MLP. Writes hout fp32 (+ hb bf16 if given).
__global__ __launch_bounds__(256, 2) void k_update(
    const float* __restrict__ hin, const _Float16* __restrict__ msg,
    const int* __restrict__ off,
    const __bf16* __restrict__ wt1, const float* __restrict__ b1,
    const __bf16* __restrict__ wt2, const float* __restrict__ b2,
    float* __restrict__ hout, __bf16* __restrict__ hbout) {
  __shared__ __align__(16) __bf16 xs[64][264];
  __shared__ int offs[65];
  const int tid = threadIdx.x;
  const int lane = tid & 63;
  const int w = tid >> 6;
  const int node0 = blockIdx.x * 64;

  if (tid < 65) {
    int n = node0 + tid;
    offs[tid] = off[n < NNODES ? n : NNODES];
  }
  // h staging (cols 128..255)
  for (int i = 0; i < 8; ++i) {
    int s = tid + i * 256;
    int r = s >> 5, o = s & 31;
    int n = node0 + r;
    float4 f = {0.f, 0.f, 0.f, 0.f};
    if (n < NNODES) f = *(const float4*)(hin + (size_t)n * 128 + o * 4);
    bf16x4 p = {(__bf16)f.x, (__bf16)f.y, (__bf16)f.z, (__bf16)f.w};
    *(bf16x4*)&xs[r][128 + o * 4] = p;
  }
  __syncthreads();  // offs ready

  // aggregation: wave w handles nodes node0+w*16+j; lane covers feats {2l,2l+1}
  const _Float16* mbase = msg + lane * 2;
#pragma unroll 1
  for (int j = 0; j < 16; ++j) {
    int beg = offs[w * 16 + j];
    int end = offs[w * 16 + j + 1];
    int deg = end - beg;
    double S0 = 0.0, S1 = 0.0;
#pragma unroll 1
    for (int d = 0; d < deg; d += 4) {
      int dm1 = deg - 1;
      int i1 = d + 1 < dm1 ? d + 1 : dm1;
      int i2 = d + 2 < dm1 ? d + 2 : dm1;
      int i3 = d + 3 < dm1 ? d + 3 : dm1;
      uint a0 = *(const uint*)(mbase + (size_t)(beg + d) * 128);
      uint a1 = *(const uint*)(mbase + (size_t)(beg + i1) * 128);
      uint a2 = *(const uint*)(mbase + (size_t)(beg + i2) * 128);
      uint a3 = *(const uint*)(mbase + (size_t)(beg + i3) * 128);
      union { uint u; _Float16 f[2]; } q0, q1, q2, q3;
      q0.u = a0; q1.u = a1; q2.u = a2; q3.u = a3;
      double e00 = exp12t((float)q0.f[0]), e01 = exp12t((float)q0.f[1]);
      double e10 = exp12t((float)q1.f[0]), e11 = exp12t((float)q1.f[1]);
      double e20 = exp12t((float)q2.f[0]), e21 = exp12t((float)q2.f[1]);
      double e30 = exp12t((float)q3.f[0]), e31 = exp12t((float)q3.f[1]);
      S0 += e00;
      S1 += e01;
      S0 += (d + 1 < deg) ? e10 : 0.0;
      S1 += (d + 1 < deg) ? e11 : 0.0;
      S0 += (d + 2 < deg) ? e20 : 0.0;
      S1 += (d + 2 < deg) ? e21 : 0.0;
      S0 += (d + 3 < deg) ? e30 : 0.0;
      S1 += (d + 3 < deg) ? e31 : 0.0;
    }
    union { uint u; __bf16 b[2]; } pk;
    pk.b[0] = (__bf16)logS12(S0);
    pk.b[1] = (__bf16)logS12(S1);
    *(uint*)&xs[w * 16 + j][2 * lane] = pk.u;
  }
  __syncthreads();

  const int lhi = lane >> 4, llo = lane & 15;
  const int cb = w * 64;

  f32x4 acc1[4][4];
#pragma unroll
  for (int rt = 0; rt < 4; rt++)
#pragma unroll
    for (int ct = 0; ct < 4; ct++) acc1[rt][ct] = (f32x4){0.f, 0.f, 0.f, 0.f};

#pragma unroll
  for (int kk = 0; kk < 8; ++kk) {
    int k = kk * 32 + lhi * 8;
    bf16x8 af[4], bfr[4];
#pragma unroll
    for (int rt = 0; rt < 4; rt++) af[rt] = *(const bf16x8*)&xs[rt * 16 + llo][k];
#pragma unroll
    for (int ct = 0; ct < 4; ct++)
      bfr[ct] = *(const bf16x8*)(wt1 + (size_t)(cb + ct * 16 + llo) * 256 + k);
#pragma unroll
    for (int rt = 0; rt < 4; rt++)
#pragma unroll
      for (int ct = 0; ct < 4; ct++)
        acc1[rt][ct] = __builtin_amdgcn_mfma_f32_16x16x32_bf16(af[rt], bfr[ct], acc1[rt][ct], 0, 0, 0);
  }
  __syncthreads();

  float b1v[4];
#pragma unroll
  for (int ct = 0; ct < 4; ct++) b1v[ct] = b1[cb + ct * 16 + llo];
#pragma unroll
  for (int rt = 0; rt < 4; rt++)
#pragma unroll
    for (int ct = 0; ct < 4; ct++)
#pragma unroll
      for (int i = 0; i < 4; i++)
        xs[rt * 16 + lhi * 4 + i][cb + ct * 16 + llo] = (__bf16)mishf(acc1[rt][ct][i] + b1v[ct]);
  __syncthreads();

  const int cb2 = w * 32;
  f32x4 acc2[4][2];
#pragma unroll
  for (int rt = 0; rt < 4; rt++)
#pragma unroll
    for (int ct = 0; ct < 2; ct++) acc2[rt][ct] = (f32x4){0.f, 0.f, 0.f, 0.f};

#pragma unroll
  for (int kk = 0; kk < 8; ++kk) {
    int k = kk * 32 + lhi * 8;
    bf16x8 af[4], bfr[2];
#pragma unroll
    for (int rt = 0; rt < 4; rt++) af[rt] = *(const bf16x8*)&xs[rt * 16 + llo][k];
#pragma unroll
    for (int ct = 0; ct < 2; ct++)
      bfr[ct] = *(const bf16x8*)(wt2 + (size_t)(cb2 + ct * 16 + llo) * 256 + k);
#pragma unroll
    for (int rt = 0; rt < 4; rt++)
#pragma unroll
      for (int ct = 0; ct < 2; ct++)
        acc2[rt][ct] = __builtin_amdgcn_mfma_f32_16x16x32_bf16(af[rt], bfr[ct], acc2[rt][ct], 0, 0, 0);
  }

  float b2v[2];
#pragma unroll
  for (int ct = 0; ct < 2; ct++) b2v[ct] = b2[cb2 + ct * 16 + llo];
#pragma unroll
  for (int rt = 0; rt < 4; rt++)
#pragma unroll
    for (int i = 0; i < 4; i++) {
      int r = rt * 16 + lhi * 4 + i;
      int n = node0 + r;
      if (n >= NNODES) continue;
#pragma unroll
      for (int ct = 0; ct < 2; ct++) {
        int col = cb2 + ct * 16 + llo;
        size_t idx = (size_t)n * 128 + col;
        float nh = hin[idx] + acc2[rt][ct][i] + b2v[ct];
        hout[idx] = nh;
        if (hbout != nullptr) hbout[idx] = (__bf16)nh;
      }
    }
}

extern "C" void kernel_launch(void* const* d_in, const int* in_sizes, int n_in,
                              void* d_out, int out_size, void* d_ws, size_t ws_size,
                              hipStream_t stream) {
  const float* h0 = (const float*)d_in[0];
  const int* at = (const int*)d_in[1];
  const float* w_in_at = (const float*)d_in[2];
  const float* b_in_at = (const float*)d_in[3];
  const float* w_out_at = (const float*)d_in[4];
  const float* b_out_at = (const float*)d_in[5];
  const int* cl = (const int*)d_in[6];
  const float* w_in_cl = (const float*)d_in[7];
  const float* b_in_cl = (const float*)d_in[8];
  const float* w_out_cl = (const float*)d_in[9];
  const float* b_out_cl = (const float*)d_in[10];
  const int* on = (const int*)d_in[11];
  const float* w_in_on = (const float*)d_in[12];
  const float* b_in_on = (const float*)d_in[13];
  const float* w_out_on = (const float*)d_in[14];
  const float* b_out_on = (const float*)d_in[15];
  const float* w_u_in = (const float*)d_in[16];
  const float* b_u_in = (const float*)d_in[17];
  const float* w_u_out = (const float*)d_in[18];
  const float* b_u_out = (const float*)d_in[19];

  float* hout = (float*)d_out;
  char* ws = (char*)d_ws;

  const size_t MSG_B = (size_t)TSLOTS * 128 * 2;  // 192,000,000
  const size_t OFF_B = 400016;
  const size_t CNT_B = 400000;
  const size_t BS_B = 1568;
  const size_t PERM_B = 3000000;
  const size_t WT_B = 786432;
  const size_t HB_B = (size_t)NNODES * 128 * 2;   // 25,600,000
  const size_t REQ2 = MSG_B + OFF_B + CNT_B + 2 * BS_B + PERM_B + WT_B;
  const size_t REQ3 = REQ2 + HB_B;

  if (ws_size < REQ2) {
    k_sentinel<<<(out_size + 255) / 256, 256, 0, stream>>>((float*)d_out, out_size);
    return;
  }

  _Float16* msg = (_Float16*)ws;
  int* off = (int*)(ws + MSG_B);
  int* cnt = (int*)(ws + MSG_B + OFF_B);
  int* bsum = (int*)(ws + MSG_B + OFF_B + CNT_B);
  int* bpre = (int*)(ws + MSG_B + OFF_B + CNT_B + BS_B);
  int* perm = (int*)(ws + MSG_B + OFF_B + CNT_B + 2 * BS_B);
  __bf16* wt = (__bf16*)(ws + MSG_B + OFF_B + CNT_B + 2 * BS_B + PERM_B);
  __bf16* hb = (ws_size >= REQ3) ? (__bf16*)(ws + REQ2) : nullptr;

  __bf16* wt_in_at = wt;
  __bf16* wt_out_at = wt + 65536;
  __bf16* wt_in_on = wt + 131072;
  __bf16* wt_out_on = wt + 196608;
  __bf16* wt_u_in = wt + 262144;
  __bf16* wt_u_out = wt + 327680;
  __bf16* wt_in_cl = wt + 360448;
  __bf16* wt_out_cl = wt + 376832;

  TransDesc td;
  const float* srcs[8] = {w_in_at, w_out_at, w_in_on, w_out_on, w_u_in, w_u_out, w_in_cl, w_out_cl};
  __bf16* dsts[8] = {wt_in_at, wt_out_at, wt_in_on, wt_out_on, wt_u_in, wt_u_out, wt_in_cl, wt_out_cl};
  int Rs[8] = {256, 256, 256, 256, 256, 256, 128, 128};
  int Cs[8] = {256, 256, 256, 256, 256, 128, 128, 128};
  int ts = 0;
  for (int m = 0; m < 8; ++m) {
    td.src[m] = srcs[m]; td.dst[m] = dsts[m]; td.R[m] = Rs[m]; td.C[m] = Cs[m];
    td.tstart[m] = ts; ts += (Rs[m] / 32) * (Cs[m] / 32);
  }
  td.tstart[8] = ts;
  k_transpose_all<<<384, 256, 0, stream>>>(td);

  if (hb) k_init<<<6250, 256, 0, stream>>>(h0, hb, NNODES * EDIM / 8);

  const int grid_rel = (150000 + 63) / 64;
  const int grid_upd = (NNODES + 63) / 64;
  const int grid_slots = (TSLOTS + 255) / 256;

  hipMemsetAsync(cnt, 0, CNT_B, stream);
  k_count<<<grid_slots, 256, 0, stream>>>(at, cl, on, cnt);
  k_bsum<<<NB, 256, 0, stream>>>(cnt, bsum);
  k_bscan<<<1, 512, 0, stream>>>(bsum, bpre, off);
  k_off<<<NB, 256, 0, stream>>>(cnt, bpre, off);
  k_fill<<<grid_slots, 256, 0, stream>>>(at, cl, on, off, cnt, perm);

  const int* perm_at = perm;
  const int* perm_cl = perm + 300000;
  const int* perm_on = perm + 450000;

  for (int l = 0; l < 4; ++l) {
    const float* hs = (l == 0) ? h0 : hout;
    k_rel2<<<grid_rel, 256, 0, stream>>>(hs, hb, at, wt_in_at, b_in_at, wt_out_at, b_out_at, msg, perm_at, 150000);
    k_rel1<<<grid_rel, 256, 0, stream>>>(hs, hb, cl, wt_in_cl, b_in_cl, wt_out_cl, b_out_cl, msg, perm_cl, 150000);
    k_rel2<<<grid_rel, 256, 0, stream>>>(hs, hb, on, wt_in_on, b_in_on, wt_out_on, b_out_on, msg, perm_on, 150000);
    k_update<<<grid_upd, 256, 0, stream>>>(hs, msg, off, wt_u_in, b_u_in, wt_u_out, b_u_out, hout, hb);
  }
}

// Round 7
// 1883.321 us; speedup vs baseline: 1.2470x; 1.0115x over previous
//
#include <hip/hip_runtime.h>
#include <hip/hip_bf16.h>
#include <math.h>

#define NNODES 100000
#define EDIM 128
#define TSLOTS 750000
#define NB 391  // ceil(NNODES/256)

typedef __bf16 bf16x8 __attribute__((ext_vector_type(8)));
typedef __bf16 bf16x4 __attribute__((ext_vector_type(4)));
typedef float f32x4 __attribute__((ext_vector_type(4)));

#define T_SCALE 17.312340490667562f    // 12*log2(e): msg stores t = y*T_SCALE
#define INV_SCALE 0.05776226504666211f // ln2/12
#define EMPTY_V (-3.0701134f)          // log(1e-16)/12

// mish(x) = x*tanh(softplus(x)) = x*(u^2+2u)/(u^2+2u+2), u=e^x
__device__ __forceinline__ float mishf(float x) {
  float u = __expf(fminf(x, 15.f));
  float num = u * (u + 2.f);
  return x * num * __builtin_amdgcn_rcpf(num + 2.f);
}

// 2^t as double (t pre-scaled by 12*log2e), fp32 exp2 + exponent bit-pack
__device__ __forceinline__ double exp12t(float t) {
  t = fmaxf(t, -20000.f);
  float ti = floorf(t);
  float m = exp2f(t - ti);
  int ei = (int)ti;
  ei = ei < -1000 ? -1000 : (ei > 1000 ? 1000 : ei);
  return (double)m * __longlong_as_double(((long long)(1023 + ei)) << 52);
}

// log(S)*ln2/12 via fp64 bit extraction; S<=0 (empty) -> log(1e-16)/12
__device__ __forceinline__ float logS12(double S) {
  if (!(S > 0.0)) return EMPTY_V;
  long long b = __double_as_longlong(S);
  int e2 = (int)((b >> 52) & 0x7FF) - 1023;
  float mf = __uint_as_float(0x3F800000u | (unsigned)((b >> 29) & 0x7FFFFF));
  return ((float)e2 + log2f(mf)) * INV_SCALE;
}

__global__ void k_sentinel(float* out, int n) {
  int i = blockIdx.x * 256 + threadIdx.x;
  if (i < n) out[i] = 1.0e6f;
}

// h0 (fp32) -> hb (bf16)
__global__ void k_init(const float* __restrict__ h0, __bf16* __restrict__ hb, int n8) {
  int i = blockIdx.x * 256 + threadIdx.x;
  if (i >= n8) return;
  float4 f0 = ((const float4*)h0)[i * 2];
  float4 f1 = ((const float4*)h0)[i * 2 + 1];
  bf16x8 p = {(__bf16)f0.x, (__bf16)f0.y, (__bf16)f0.z, (__bf16)f0.w,
              (__bf16)f1.x, (__bf16)f1.y, (__bf16)f1.z, (__bf16)f1.w};
  *(bf16x8*)(hb + (size_t)i * 8) = p;
}

struct TransDesc {
  const float* src[8];
  __bf16* dst[8];
  int R[8];
  int C[8];
  int tstart[9];
};

__global__ void k_transpose_all(TransDesc td) {
  __shared__ float tile[32][33];
  int b = blockIdx.x;
  int m = 0;
  while (m < 7 && b >= td.tstart[m + 1]) m++;
  int t = b - td.tstart[m];
  int R = td.R[m], C = td.C[m];
  int tcols = C >> 5;
  int by = t / tcols, bx = t - by * tcols;
  int tx = threadIdx.x & 31, ty = threadIdx.x >> 5;
  const float* src = td.src[m];
  __bf16* dst = td.dst[m];
  for (int i = 0; i < 32; i += 8)
    tile[ty + i][tx] = src[(size_t)(by * 32 + ty + i) * C + bx * 32 + tx];
  __syncthreads();
  for (int i = 0; i < 32; i += 8)
    dst[(size_t)(bx * 32 + ty + i) * R + by * 32 + tx] = (__bf16)tile[tx][ty + i];
}

// ================= CSR build =================
__device__ __forceinline__ int slot_node(int s, const int* at, const int* cl, const int* on) {
  if (s < 300000) return at[s];
  if (s < 450000) return cl[s - 300000];
  return on[s - 450000];
}

__global__ void k_count(const int* __restrict__ at, const int* __restrict__ cl,
                        const int* __restrict__ on, int* __restrict__ cnt) {
  int s = blockIdx.x * 256 + threadIdx.x;
  if (s >= TSLOTS) return;
  atomicAdd(&cnt[slot_node(s, at, cl, on)], 1);
}

__global__ void k_bsum(const int* __restrict__ cnt, int* __restrict__ bsum) {
  __shared__ int sm[256];
  int n = blockIdx.x * 256 + threadIdx.x;
  sm[threadIdx.x] = (n < NNODES) ? cnt[n] : 0;
  __syncthreads();
  for (int st = 128; st > 0; st >>= 1) {
    if (threadIdx.x < st) sm[threadIdx.x] += sm[threadIdx.x + st];
    __syncthreads();
  }
  if (threadIdx.x == 0) bsum[blockIdx.x] = sm[0];
}

__global__ void k_bscan(const int* __restrict__ bsum, int* __restrict__ bpre,
                        int* __restrict__ off) {
  __shared__ int sm[512];
  int t = threadIdx.x;
  int v = (t < NB) ? bsum[t] : 0;
  sm[t] = v;
  __syncthreads();
  for (int st = 1; st < 512; st <<= 1) {
    int x = (t >= st) ? sm[t - st] : 0;
    __syncthreads();
    sm[t] += x;
    __syncthreads();
  }
  if (t < NB) bpre[t] = sm[t] - v;
  if (t == NB - 1) off[NNODES] = sm[t];
}

__global__ void k_off(const int* __restrict__ cnt, const int* __restrict__ bpre,
                      int* __restrict__ off) {
  __shared__ int sm[256];
  int n = blockIdx.x * 256 + threadIdx.x;
  int v = (n < NNODES) ? cnt[n] : 0;
  sm[threadIdx.x] = v;
  __syncthreads();
  for (int st = 1; st < 256; st <<= 1) {
    int t = (threadIdx.x >= st) ? sm[threadIdx.x - st] : 0;
    __syncthreads();
    sm[threadIdx.x] += t;
    __syncthreads();
  }
  if (n < NNODES) off[n] = bpre[blockIdx.x] + sm[threadIdx.x] - v;
}

__global__ void k_fill(const int* __restrict__ at, const int* __restrict__ cl,
                       const int* __restrict__ on, const int* __restrict__ off,
                       int* __restrict__ cnt, int* __restrict__ perm) {
  int s = blockIdx.x * 256 + threadIdx.x;
  if (s >= TSLOTS) return;
  int node = slot_node(s, at, cl, on);
  int pos = atomicAdd(&cnt[node], -1) - 1;
  perm[s] = off[node] + pos;
}

// ================= relation kernels =================
__global__ __launch_bounds__(256, 4) void k_rel2(
    const float* __restrict__ hf, const __bf16* __restrict__ hb,
    const int* __restrict__ av,
    const __bf16* __restrict__ wt1, const float* __restrict__ b1,
    const __bf16* __restrict__ wt2, const float* __restrict__ b2,
    _Float16* __restrict__ msg, const int* __restrict__ permrel, int A) {
  __shared__ __align__(16) __bf16 xs[64][264];
  __shared__ int avs[128];
  __shared__ int prm[128];
  const int tid = threadIdx.x;
  const int lane = tid & 63;
  const int w = tid >> 6;
  const int row0 = blockIdx.x * 64;

  if (tid < 128) {
    int i2 = row0 * 2 + tid;
    avs[tid] = (i2 < 2 * A) ? av[i2] : 0;
    prm[tid] = (i2 < 2 * A) ? permrel[i2] : 0;
  }
  if (hb != nullptr) {
    for (int i = 0; i < 8; ++i) {
      int s = tid + i * 256;
      int r = s >> 5, o = s & 31;
      int a = row0 + r;
      uint4 v = {0, 0, 0, 0};
      if (a < A) {
        int node = av[2 * a + (o >> 4)];
        v = *(const uint4*)(hb + (size_t)node * 128 + (o & 15) * 8);
      }
      *(uint4*)&xs[r][o * 8] = v;
    }
  } else {
    for (int i = 0; i < 16; ++i) {
      int s = tid + i * 256;
      int r = s >> 6, o = s & 63;
      int a = row0 + r;
      float4 f = {0.f, 0.f, 0.f, 0.f};
      if (a < A) {
        int node = av[2 * a + (o >> 5)];
        f = *(const float4*)(hf + (size_t)node * 128 + (o & 31) * 4);
      }
      bf16x4 p = {(__bf16)f.x, (__bf16)f.y, (__bf16)f.z, (__bf16)f.w};
      *(bf16x4*)&xs[r][o * 4] = p;
    }
  }
  __syncthreads();

  const int lhi = lane >> 4, llo = lane & 15;
  const int cb = w * 64;

  f32x4 acc1[4][4];
#pragma unroll
  for (int rt = 0; rt < 4; rt++)
#pragma unroll
    for (int ct = 0; ct < 4; ct++) acc1[rt][ct] = (f32x4){0.f, 0.f, 0.f, 0.f};

#pragma unroll
  for (int kk = 0; kk < 8; ++kk) {
    int k = kk * 32 + lhi * 8;
    bf16x8 af[4], bfr[4];
#pragma unroll
    for (int rt = 0; rt < 4; rt++) af[rt] = *(const bf16x8*)&xs[rt * 16 + llo][k];
#pragma unroll
    for (int ct = 0; ct < 4; ct++)
      bfr[ct] = *(const bf16x8*)(wt1 + (size_t)(cb + ct * 16 + llo) * 256 + k);
#pragma unroll
    for (int rt = 0; rt < 4; rt++)
#pragma unroll
      for (int ct = 0; ct < 4; ct++)
        acc1[rt][ct] = __builtin_amdgcn_mfma_f32_16x16x32_bf16(af[rt], bfr[ct], acc1[rt][ct], 0, 0, 0);
  }
  __syncthreads();

  float b1v[4];
#pragma unroll
  for (int ct = 0; ct < 4; ct++) b1v[ct] = b1[cb + ct * 16 + llo];
#pragma unroll
  for (int rt = 0; rt < 4; rt++)
#pragma unroll
    for (int ct = 0; ct < 4; ct++)
#pragma unroll
      for (int i = 0; i < 4; i++)
        xs[rt * 16 + lhi * 4 + i][cb + ct * 16 + llo] = (__bf16)mishf(acc1[rt][ct][i] + b1v[ct]);
  __syncthreads();

  f32x4 acc2[4][4];
#pragma unroll
  for (int rt = 0; rt < 4; rt++)
#pragma unroll
    for (int ct = 0; ct < 4; ct++) acc2[rt][ct] = (f32x4){0.f, 0.f, 0.f, 0.f};

#pragma unroll
  for (int kk = 0; kk < 8; ++kk) {
    int k = kk * 32 + lhi * 8;
    bf16x8 af[4], bfr[4];
#pragma unroll
    for (int rt = 0; rt < 4; rt++) af[rt] = *(const bf16x8*)&xs[rt * 16 + llo][k];
#pragma unroll
    for (int ct = 0; ct < 4; ct++)
      bfr[ct] = *(const bf16x8*)(wt2 + (size_t)(cb + ct * 16 + llo) * 256 + k);
#pragma unroll
    for (int rt = 0; rt < 4; rt++)
#pragma unroll
      for (int ct = 0; ct < 4; ct++)
        acc2[rt][ct] = __builtin_amdgcn_mfma_f32_16x16x32_bf16(af[rt], bfr[ct], acc2[rt][ct], 0, 0, 0);
  }
  __syncthreads();

  float b2v[4];
#pragma unroll
  for (int ct = 0; ct < 4; ct++) b2v[ct] = b2[cb + ct * 16 + llo];
  ushort* zs = (ushort*)&xs[0][0];  // row stride 264
#pragma unroll
  for (int rt = 0; rt < 4; rt++)
#pragma unroll
    for (int ct = 0; ct < 4; ct++)
#pragma unroll
      for (int i = 0; i < 4; i++) {
        int r = rt * 16 + lhi * 4 + i;
        int col = cb + ct * 16 + llo;
        union { ushort u; _Float16 f; } cv;
        cv.f = (_Float16)(acc2[rt][ct][i] + b2v[ct]);
        zs[r * 264 + col] = cv.u;
      }
  __syncthreads();

  for (int i = 0; i < 8; ++i) {
    int s = tid + i * 256;
    int sr = s >> 4;   // slot-row 0..127
    int c = s & 15;    // 8-feat chunk
    int a = row0 + (sr >> 1);
    if (a < A) {
      int node = avs[sr];
      int rr = sr >> 1, c0 = (sr & 1) * 128 + c * 8;
      float hv[8];
      if (hb != nullptr) {
        union { uint4 u; __bf16 b[8]; } hu;
        hu.u = *(const uint4*)(hb + (size_t)node * 128 + c * 8);
#pragma unroll
        for (int k = 0; k < 8; ++k) hv[k] = (float)hu.b[k];
      } else {
        const float* hp = hf + (size_t)node * 128 + c * 8;
        float4 h0 = *(const float4*)hp;
        float4 h1 = *(const float4*)(hp + 4);
        hv[0] = h0.x; hv[1] = h0.y; hv[2] = h0.z; hv[3] = h0.w;
        hv[4] = h1.x; hv[5] = h1.y; hv[6] = h1.z; hv[7] = h1.w;
      }
      union { uint4 u; _Float16 f[8]; } zu, yu;
      zu.u = *(const uint4*)&zs[rr * 264 + c0];
#pragma unroll
      for (int k = 0; k < 8; ++k)
        yu.f[k] = (_Float16)(fminf(((float)zu.f[k] + hv[k]) * T_SCALE, 60000.f));
      *(uint4*)(msg + (size_t)prm[sr] * 128 + c * 8) = yu.u;
    }
  }
}

__global__ __launch_bounds__(256, 4) void k_rel1(
    const float* __restrict__ hf, const __bf16* __restrict__ hb,
    const int* __restrict__ av,
    const __bf16* __restrict__ wt1, const float* __restrict__ b1,
    const __bf16* __restrict__ wt2, const float* __restrict__ b2,
    _Float16* __restrict__ msg, const int* __restrict__ permrel, int A) {
  __shared__ __align__(16) __bf16 xs[64][136];
  __shared__ int avs[64];
  __shared__ int prm[64];
  const int tid = threadIdx.x;
  const int lane = tid & 63;
  const int w = tid >> 6;
  const int row0 = blockIdx.x * 64;

  if (tid < 64) {
    int a = row0 + tid;
    avs[tid] = (a < A) ? av[a] : 0;
    prm[tid] = (a < A) ? permrel[a] : 0;
  }
  if (hb != nullptr) {
    for (int i = 0; i < 4; ++i) {
      int s = tid + i * 256;
      int r = s >> 4, o = s & 15;
      int a = row0 + r;
      uint4 v = {0, 0, 0, 0};
      if (a < A) {
        int node = av[a];
        v = *(const uint4*)(hb + (size_t)node * 128 + o * 8);
      }
      *(uint4*)&xs[r][o * 8] = v;
    }
  } else {
    for (int i = 0; i < 8; ++i) {
      int s = tid + i * 256;
      int r = s >> 5, o = s & 31;
      int a = row0 + r;
      float4 f = {0.f, 0.f, 0.f, 0.f};
      if (a < A) {
        int node = av[a];
        f = *(const float4*)(hf + (size_t)node * 128 + o * 4);
      }
      bf16x4 p = {(__bf16)f.x, (__bf16)f.y, (__bf16)f.z, (__bf16)f.w};
      *(bf16x4*)&xs[r][o * 4] = p;
    }
  }
  __syncthreads();

  const int lhi = lane >> 4, llo = lane & 15;
  const int cb = w * 32;

  f32x4 acc1[4][2];
#pragma unroll
  for (int rt = 0; rt < 4; rt++)
#pragma unroll
    for (int ct = 0; ct < 2; ct++) acc1[rt][ct] = (f32x4){0.f, 0.f, 0.f, 0.f};

#pragma unroll
  for (int kk = 0; kk < 4; ++kk) {
    int k = kk * 32 + lhi * 8;
    bf16x8 af[4], bfr[2];
#pragma unroll
    for (int rt = 0; rt < 4; rt++) af[rt] = *(const bf16x8*)&xs[rt * 16 + llo][k];
#pragma unroll
    for (int ct = 0; ct < 2; ct++)
      bfr[ct] = *(const bf16x8*)(wt1 + (size_t)(cb + ct * 16 + llo) * 128 + k);
#pragma unroll
    for (int rt = 0; rt < 4; rt++)
#pragma unroll
      for (int ct = 0; ct < 2; ct++)
        acc1[rt][ct] = __builtin_amdgcn_mfma_f32_16x16x32_bf16(af[rt], bfr[ct], acc1[rt][ct], 0, 0, 0);
  }
  __syncthreads();

  float b1v[2];
#pragma unroll
  for (int ct = 0; ct < 2; ct++) b1v[ct] = b1[cb + ct * 16 + llo];
#pragma unroll
  for (int rt = 0; rt < 4; rt++)
#pragma unroll
    for (int ct = 0; ct < 2; ct++)
#pragma unroll
      for (int i = 0; i < 4; i++)
        xs[rt * 16 + lhi * 4 + i][cb + ct * 16 + llo] = (__bf16)mishf(acc1[rt][ct][i] + b1v[ct]);
  __syncthreads();

  f32x4 acc2[4][2];
#pragma unroll
  for (int rt = 0; rt < 4; rt++)
#pragma unroll
    for (int ct = 0; ct < 2; ct++) acc2[rt][ct] = (f32x4){0.f, 0.f, 0.f, 0.f};

#pragma unroll
  for (int kk = 0; kk < 4; ++kk) {
    int k = kk * 32 + lhi * 8;
    bf16x8 af[4], bfr[2];
#pragma unroll
    for (int rt = 0; rt < 4; rt++) af[rt] = *(const bf16x8*)&xs[rt * 16 + llo][k];
#pragma unroll
    for (int ct = 0; ct < 2; ct++)
      bfr[ct] = *(const bf16x8*)(wt2 + (size_t)(cb + ct * 16 + llo) * 128 + k);
#pragma unroll
    for (int rt = 0; rt < 4; rt++)
#pragma unroll
      for (int ct = 0; ct < 2; ct++)
        acc2[rt][ct] = __builtin_amdgcn_mfma_f32_16x16x32_bf16(af[rt], bfr[ct], acc2[rt][ct], 0, 0, 0);
  }
  __syncthreads();

  float b2v[2];
#pragma unroll
  for (int ct = 0; ct < 2; ct++) b2v[ct] = b2[cb + ct * 16 + llo];
  ushort* zs = (ushort*)&xs[0][0];  // row stride 136
#pragma unroll
  for (int rt = 0; rt < 4; rt++)
#pragma unroll
    for (int ct = 0; ct < 2; ct++)
#pragma unroll
      for (int i = 0; i < 4; i++) {
        int r = rt * 16 + lhi * 4 + i;
        int col = cb + ct * 16 + llo;
        union { ushort u; _Float16 f; } cv;
        cv.f = (_Float16)(acc2[rt][ct][i] + b2v[ct]);
        zs[r * 136 + col] = cv.u;
      }
  __syncthreads();

  for (int i = 0; i < 4; ++i) {
    int s = tid + i * 256;
    int sr = s >> 4;  // 0..63
    int c = s & 15;
    int a = row0 + sr;
    if (a < A) {
      int node = avs[sr];
      float hv[8];
      if (hb != nullptr) {
        union { uint4 u; __bf16 b[8]; } hu;
        hu.u = *(const uint4*)(hb + (size_t)node * 128 + c * 8);
#pragma unroll
        for (int k = 0; k < 8; ++k) hv[k] = (float)hu.b[k];
      } else {
        const float* hp = hf + (size_t)node * 128 + c * 8;
        float4 h0 = *(const float4*)hp;
        float4 h1 = *(const float4*)(hp + 4);
        hv[0] = h0.x; hv[1] = h0.y; hv[2] = h0.z; hv[3] = h0.w;
        hv[4] = h1.x; hv[5] = h1.y; hv[6] = h1.z; hv[7] = h1.w;
      }
      union { uint4 u; _Float16 f[8]; } zu, yu;
      zu.u = *(const uint4*)&zs[sr * 136 + c * 8];
#pragma unroll
      for (int k = 0; k < 8; ++k)
        yu.f[k] = (_Float16)(fminf(((float)zu.f[k] + hv[k]) * T_SCALE, 60000.f));
      *(uint4*)(msg + (size_t)prm[sr] * 128 + c * 8) = yu.u;
    }
  }
}

// ======= aggregation: streaming fp64 sum of 2^t, 2 rows per wave-inst =======
// block = 4 waves x 8 nodes. lane: fl=lane&31 -> feats fl*4..+4, p=lane>>5 -> row parity.
// wave-inst reads 512 B (2 consecutive CSR rows: lanes 0-31 row d, lanes 32-63 row d+1);
// node-end: one shfl_xor(32) fp64 butterfly.
__global__ __launch_bounds__(256, 8) void k_agg(
    const _Float16* __restrict__ msg, const int* __restrict__ off,
    __bf16* __restrict__ mm) {
  __shared__ int offs[33];
  const int tid = threadIdx.x;
  const int lane = tid & 63;
  const int w = tid >> 6;
  const int node0 = blockIdx.x * 32;
  if (tid < 33) {
    int n = node0 + tid;
    offs[tid] = off[n < NNODES ? n : NNODES];
  }
  __syncthreads();

  const int fl = lane & 31;
  const int p = lane >> 5;
  const _Float16* mb = msg + fl * 4;  // parity enters via rp = d + p ONLY (r6 bug: was also +p*128)

#pragma unroll 1
  for (int j = 0; j < 8; ++j) {
    int n = node0 + w * 8 + j;
    if (n >= NNODES) break;
    int beg = offs[w * 8 + j];
    int deg = offs[w * 8 + j + 1] - beg;
    double S0 = 0.0, S1 = 0.0, S2 = 0.0, S3 = 0.0;
#pragma unroll 1
    for (int d = 0; d < deg; d += 2) {
      int rp = d + p;
      int rc = rp < deg - 1 ? rp : deg - 1;
      uint2 v = *(const uint2*)(mb + (size_t)(beg + rc) * 128);
      if (rp >= deg) { v.x = 0xFC00FC00u; v.y = 0xFC00FC00u; }  // fp16 -inf -> ~0
      union { uint2 u; _Float16 f[4]; } q;
      q.u = v;
      S0 += exp12t((float)q.f[0]);
      S1 += exp12t((float)q.f[1]);
      S2 += exp12t((float)q.f[2]);
      S3 += exp12t((float)q.f[3]);
    }
    S0 += __shfl_xor(S0, 32);
    S1 += __shfl_xor(S1, 32);
    S2 += __shfl_xor(S2, 32);
    S3 += __shfl_xor(S3, 32);
    if (p == 0) {
      bf16x4 r;
      r[0] = (__bf16)logS12(S0);
      r[1] = (__bf16)logS12(S1);
      r[2] = (__bf16)logS12(S2);
      r[3] = (__bf16)logS12(S3);
      *(bf16x4*)(mm + (size_t)n * 128 + fl * 4) = r;
    }
  }
}

// ======= update MLP: xu=[max_msg(bf16), h] -> mish MLP -> hout = hin + upd =======
__global__ __launch_bounds__(256, 4) void k_mlp(
    const float* __restrict__ hin, const __bf16* __restrict__ mm,
    const __bf16* __restrict__ wt1, const float* __restrict__ b1,
    const __bf16* __restrict__ wt2, const float* __restrict__ b2,
    float* __restrict__ hout, __bf16* __restrict__ hbout) {
  __shared__ __align__(16) __bf16 xs[64][264];
  const int tid = threadIdx.x;
  const int lane = tid & 63;
  const int w = tid >> 6;
  const int node0 = blockIdx.x * 64;

  // max_msg staging (cols 0..127), already bf16
  for (int i = 0; i < 4; ++i) {
    int s = tid + i * 256;
    int r = s >> 4, o = s & 15;
    int n = node0 + r;
    uint4 v = {0, 0, 0, 0};
    if (n < NNODES) v = *(const uint4*)(mm + (size_t)n * 128 + o * 8);
    *(uint4*)&xs[r][o * 8] = v;
  }
  // h staging (cols 128..255)
  for (int i = 0; i < 8; ++i) {
    int s = tid + i * 256;
    int r = s >> 5, o = s & 31;
    int n = node0 + r;
    float4 f = {0.f, 0.f, 0.f, 0.f};
    if (n < NNODES) f = *(const float4*)(hin + (size_t)n * 128 + o * 4);
    bf16x4 p = {(__bf16)f.x, (__bf16)f.y, (__bf16)f.z, (__bf16)f.w};
    *(bf16x4*)&xs[r][128 + o * 4] = p;
  }
  __syncthreads();

  const int lhi = lane >> 4, llo = lane & 15;
  const int cb = w * 64;

  f32x4 acc1[4][4];
#pragma unroll
  for (int rt = 0; rt < 4; rt++)
#pragma unroll
    for (int ct = 0; ct < 4; ct++) acc1[rt][ct] = (f32x4){0.f, 0.f, 0.f, 0.f};

#pragma unroll
  for (int kk = 0; kk < 8; ++kk) {
    int k = kk * 32 + lhi * 8;
    bf16x8 af[4], bfr[4];
#pragma unroll
    for (int rt = 0; rt < 4; rt++) af[rt] = *(const bf16x8*)&xs[rt * 16 + llo][k];
#pragma unroll
    for (int ct = 0; ct < 4; ct++)
      bfr[ct] = *(const bf16x8*)(wt1 + (size_t)(cb + ct * 16 + llo) * 256 + k);
#pragma unroll
    for (int rt = 0; rt < 4; rt++)
#pragma unroll
      for (int ct = 0; ct < 4; ct++)
        acc1[rt][ct] = __builtin_amdgcn_mfma_f32_16x16x32_bf16(af[rt], bfr[ct], acc1[rt][ct], 0, 0, 0);
  }
  __syncthreads();

  float b1v[4];
#pragma unroll
  for (int ct = 0; ct < 4; ct++) b1v[ct] = b1[cb + ct * 16 + llo];
#pragma unroll
  for (int rt = 0; rt < 4; rt++)
#pragma unroll
    for (int ct = 0; ct < 4; ct++)
#pragma unroll
      for (int i = 0; i < 4; i++)
        xs[rt * 16 + lhi * 4 + i][cb + ct * 16 + llo] = (__bf16)mishf(acc1[rt][ct][i] + b1v[ct]);
  __syncthreads();

  const int cb2 = w * 32;
  f32x4 acc2[4][2];
#pragma unroll
  for (int rt = 0; rt < 4; rt++)
#pragma unroll
    for (int ct = 0; ct < 2; ct++) acc2[rt][ct] = (f32x4){0.f, 0.f, 0.f, 0.f};

#pragma unroll
  for (int kk = 0; kk < 8; ++kk) {
    int k = kk * 32 + lhi * 8;
    bf16x8 af[4], bfr[2];
#pragma unroll
    for (int rt = 0; rt < 4; rt++) af[rt] = *(const bf16x8*)&xs[rt * 16 + llo][k];
#pragma unroll
    for (int ct = 0; ct < 2; ct++)
      bfr[ct] = *(const bf16x8*)(wt2 + (size_t)(cb2 + ct * 16 + llo) * 256 + k);
#pragma unroll
    for (int rt = 0; rt < 4; rt++)
#pragma unroll
      for (int ct = 0; ct < 2; ct++)
        acc2[rt][ct] = __builtin_amdgcn_mfma_f32_16x16x32_bf16(af[rt], bfr[ct], acc2[rt][ct], 0, 0, 0);
  }

  float b2v[2];
#pragma unroll
  for (int ct = 0; ct < 2; ct++) b2v[ct] = b2[cb2 + ct * 16 + llo];
#pragma unroll
  for (int rt = 0; rt < 4; rt++)
#pragma unroll
    for (int i = 0; i < 4; i++) {
      int r = rt * 16 + lhi * 4 + i;
      int n = node0 + r;
      if (n >= NNODES) continue;
#pragma unroll
      for (int ct = 0; ct < 2; ct++) {
        int col = cb2 + ct * 16 + llo;
        size_t idx = (size_t)n * 128 + col;
        float nh = hin[idx] + acc2[rt][ct][i] + b2v[ct];
        hout[idx] = nh;
        if (hbout != nullptr) hbout[idx] = (__bf16)nh;
      }
    }
}

extern "C" void kernel_launch(void* const* d_in, const int* in_sizes, int n_in,
                              void* d_out, int out_size, void* d_ws, size_t ws_size,
                              hipStream_t stream) {
  const float* h0 = (const float*)d_in[0];
  const int* at = (const int*)d_in[1];
  const float* w_in_at = (const float*)d_in[2];
  const float* b_in_at = (const float*)d_in[3];
  const float* w_out_at = (const float*)d_in[4];
  const float* b_out_at = (const float*)d_in[5];
  const int* cl = (const int*)d_in[6];
  const float* w_in_cl = (const float*)d_in[7];
  const float* b_in_cl = (const float*)d_in[8];
  const float* w_out_cl = (const float*)d_in[9];
  const float* b_out_cl = (const float*)d_in[10];
  const int* on = (const int*)d_in[11];
  const float* w_in_on = (const float*)d_in[12];
  const float* b_in_on = (const float*)d_in[13];
  const float* w_out_on = (const float*)d_in[14];
  const float* b_out_on = (const float*)d_in[15];
  const float* w_u_in = (const float*)d_in[16];
  const float* b_u_in = (const float*)d_in[17];
  const float* w_u_out = (const float*)d_in[18];
  const float* b_u_out = (const float*)d_in[19];

  float* hout = (float*)d_out;
  char* ws = (char*)d_ws;

  const size_t MSG_B = (size_t)TSLOTS * 128 * 2;  // 192,000,000
  const size_t OFF_B = 400016;
  const size_t CNT_B = 400000;
  const size_t BS_B = 1568;
  const size_t PERM_B = 3000000;
  const size_t WT_B = 786432;
  const size_t MM_B = (size_t)NNODES * 128 * 2;   // 25,600,000 (max_msg bf16)
  const size_t HB_B = (size_t)NNODES * 128 * 2;   // 25,600,000 (h bf16 shadow)
  const size_t REQ2 = MSG_B + OFF_B + CNT_B + 2 * BS_B + PERM_B + WT_B + MM_B;
  const size_t REQ3 = REQ2 + HB_B;

  if (ws_size < REQ2) {
    k_sentinel<<<(out_size + 255) / 256, 256, 0, stream>>>((float*)d_out, out_size);
    return;
  }

  _Float16* msg = (_Float16*)ws;
  int* off = (int*)(ws + MSG_B);
  int* cnt = (int*)(ws + MSG_B + OFF_B);
  int* bsum = (int*)(ws + MSG_B + OFF_B + CNT_B);
  int* bpre = (int*)(ws + MSG_B + OFF_B + CNT_B + BS_B);
  int* perm = (int*)(ws + MSG_B + OFF_B + CNT_B + 2 * BS_B);
  __bf16* wt = (__bf16*)(ws + MSG_B + OFF_B + CNT_B + 2 * BS_B + PERM_B);
  __bf16* mm = (__bf16*)(ws + MSG_B + OFF_B + CNT_B + 2 * BS_B + PERM_B + WT_B);
  __bf16* hb = (ws_size >= REQ3) ? (__bf16*)(ws + REQ2) : nullptr;

  __bf16* wt_in_at = wt;
  __bf16* wt_out_at = wt + 65536;
  __bf16* wt_in_on = wt + 131072;
  __bf16* wt_out_on = wt + 196608;
  __bf16* wt_u_in = wt + 262144;
  __bf16* wt_u_out = wt + 327680;
  __bf16* wt_in_cl = wt + 360448;
  __bf16* wt_out_cl = wt + 376832;

  TransDesc td;
  const float* srcs[8] = {w_in_at, w_out_at, w_in_on, w_out_on, w_u_in, w_u_out, w_in_cl, w_out_cl};
  __bf16* dsts[8] = {wt_in_at, wt_out_at, wt_in_on, wt_out_on, wt_u_in, wt_u_out, wt_in_cl, wt_out_cl};
  int Rs[8] = {256, 256, 256, 256, 256, 256, 128, 128};
  int Cs[8] = {256, 256, 256, 256, 256, 128, 128, 128};
  int ts = 0;
  for (int m = 0; m < 8; ++m) {
    td.src[m] = srcs[m]; td.dst[m] = dsts[m]; td.R[m] = Rs[m]; td.C[m] = Cs[m];
    td.tstart[m] = ts; ts += (Rs[m] / 32) * (Cs[m] / 32);
  }
  td.tstart[8] = ts;
  k_transpose_all<<<384, 256, 0, stream>>>(td);

  if (hb) k_init<<<6250, 256, 0, stream>>>(h0, hb, NNODES * EDIM / 8);

  const int grid_rel = (150000 + 63) / 64;       // 2344
  const int grid_mlp = (NNODES + 63) / 64;       // 1563
  const int grid_agg = (NNODES + 31) / 32;       // 3125
  const int grid_slots = (TSLOTS + 255) / 256;   // 2930

  hipMemsetAsync(cnt, 0, CNT_B, stream);
  k_count<<<grid_slots, 256, 0, stream>>>(at, cl, on, cnt);
  k_bsum<<<NB, 256, 0, stream>>>(cnt, bsum);
  k_bscan<<<1, 512, 0, stream>>>(bsum, bpre, off);
  k_off<<<NB, 256, 0, stream>>>(cnt, bpre, off);
  k_fill<<<grid_slots, 256, 0, stream>>>(at, cl, on, off, cnt, perm);

  const int* perm_at = perm;
  const int* perm_cl = perm + 300000;
  const int* perm_on = perm + 450000;

  for (int l = 0; l < 4; ++l) {
    const float* hs = (l == 0) ? h0 : hout;
    k_rel2<<<grid_rel, 256, 0, stream>>>(hs, hb, at, wt_in_at, b_in_at, wt_out_at, b_out_at, msg, perm_at, 150000);
    k_rel1<<<grid_rel, 256, 0, stream>>>(hs, hb, cl, wt_in_cl, b_in_cl, wt_out_cl, b_out_cl, msg, perm_cl, 150000);
    k_rel2<<<grid_rel, 256, 0, stream>>>(hs, hb, on, wt_in_on, b_in_on, wt_out_on, b_out_on, msg, perm_on, 150000);
    k_agg<<<grid_agg, 256, 0, stream>>>(msg, off, mm);
    k_mlp<<<grid_mlp, 256, 0, stream>>>(hs, mm, wt_u_in, b_u_in, wt_u_out, b_u_out, hout, hb);
  }
}